// Round 3
// baseline (31589.136 us; speedup 1.0000x reference)
//
#include <hip/hip_runtime.h>

#define Bd 64
#define Td 64
#define Sd 128
#define Hd 512
#define Ed 256
#define Vd 10000
#define NBLK 256

__device__ __forceinline__ float fast_tanh(float x) {
  float e = __expf(-2.0f * fabsf(x));
  float r = (1.0f - e) / (1.0f + e);
  return copysignf(r, x);
}
__device__ __forceinline__ float fast_sigmoid(float x) {
  return 1.0f / (1.0f + __expf(-x));
}

// software grid barrier: arrive[NBLK] slots + go flag, monotonic epoch
__device__ __forceinline__ void gbar(int* arrive, int* go, int ep, int blk, int tid) {
  __syncthreads();
  if (tid == 0) {
    __threadfence();
    __hip_atomic_store(&arrive[blk], ep, __ATOMIC_RELEASE, __HIP_MEMORY_SCOPE_AGENT);
  }
  if (blk == 0) {
    while (__hip_atomic_load(&arrive[tid], __ATOMIC_ACQUIRE,
                             __HIP_MEMORY_SCOPE_AGENT) < ep) {
      __builtin_amdgcn_s_sleep(1);
    }
    __syncthreads();
    if (tid == 0)
      __hip_atomic_store(go, ep, __ATOMIC_RELEASE, __HIP_MEMORY_SCOPE_AGENT);
  }
  if (tid == 0) {
    while (__hip_atomic_load(go, __ATOMIC_ACQUIRE, __HIP_MEMORY_SCOPE_AGENT) < ep) {
      __builtin_amdgcn_s_sleep(1);
    }
  }
  __syncthreads();
}

// C[M,N] = A[M,K] @ W[N,K]^T (+bias). SWAP: out row m=(t*64+b) -> (b*T+t).
template <bool SWAP, bool BIAS>
__global__ void k_gemm_abt(const float* __restrict__ A, const float* __restrict__ W,
                           const float* __restrict__ bias, float* __restrict__ C,
                           int M, int N, int K) {
  __shared__ __align__(16) float As[16][64];
  __shared__ __align__(16) float Ws[16][64];
  int m0 = blockIdx.x * 64, n0 = blockIdx.y * 64;
  int tid = threadIdx.x;
  int tx = tid & 15, ty = tid >> 4;
  float acc[4][4] = {};
  for (int k0 = 0; k0 < K; k0 += 16) {
#pragma unroll
    for (int i = 0; i < 4; i++) {
      int e = tid + i * 256;
      int r = e >> 4, c = e & 15;
      As[c][r] = A[(long)(m0 + r) * K + k0 + c];
    }
#pragma unroll
    for (int i = 0; i < 4; i++) {
      int e = tid + i * 256;
      int r = e >> 4, c = e & 15;
      int n = n0 + r;
      Ws[c][r] = (n < N) ? W[(long)n * K + k0 + c] : 0.0f;
    }
    __syncthreads();
#pragma unroll
    for (int k = 0; k < 16; k++) {
      float a_[4], w_[4];
#pragma unroll
      for (int i = 0; i < 4; i++) a_[i] = As[k][ty * 4 + i];
#pragma unroll
      for (int j = 0; j < 4; j++) w_[j] = Ws[k][tx * 4 + j];
#pragma unroll
      for (int i = 0; i < 4; i++)
#pragma unroll
        for (int j = 0; j < 4; j++) acc[i][j] += a_[i] * w_[j];
    }
    __syncthreads();
  }
#pragma unroll
  for (int i = 0; i < 4; i++) {
    int m = m0 + ty * 4 + i;
#pragma unroll
    for (int j = 0; j < 4; j++) {
      int n = n0 + tx * 4 + j;
      if (n < N) {
        float v = acc[i][j];
        if (BIAS) v += bias[n];
        long idx;
        if (SWAP) {
          int t_ = m >> 6, b_ = m & 63;
          idx = ((long)(b_ * Td + t_)) * N + n;
        } else {
          idx = (long)m * N + n;
        }
        C[idx] = v;
      }
    }
  }
}

// GRU cell phase inside the fused kernel.
// block = (bh in 0..1, jg in 0..127): 32 b x 4 j. thread = (b_=tid&31, s5=tid>>5):
// s5 -> (jl = s5&3, kh = s5>>2): K split in interleaved 64-chunks by kh.
template <bool C0>
__device__ void cell_phase(int blk, int tid, float (*As)[32][68], int* xs,
                           const float* __restrict__ A1, const float* __restrict__ emb,
                           const int* __restrict__ x, int t, const float* __restrict__ A2,
                           const float* __restrict__ Wih, const float* __restrict__ Whh,
                           const float* __restrict__ bih, const float* __restrict__ bhh,
                           float* __restrict__ hout, float* __restrict__ ys) {
  const int KIH = C0 ? (Hd + Ed) : Hd;
  int bh = blk >> 7, jg = blk & 127;
  int bbase = bh * 32;
  int b_ = tid & 31, s5 = tid >> 5;
  int jl = s5 & 3, kh = s5 >> 2;
  int j = jg * 4 + jl;
  int b = bbase + b_;
  if (C0) {
    if (tid < 32) xs[tid] = x[(bbase + tid) * Td + t];
  }
  __syncthreads();
  float pr = 0.f, pz = 0.f, pin = 0.f, phn = 0.f;
  const float* wr = &Wih[(long)j * KIH];
  const float* wz = &Wih[(long)(Hd + j) * KIH];
  const float* wn = &Wih[(long)(2 * Hd + j) * KIH];
  // input-hidden chunks (pairs of 64-k chunks)
  for (int cp = 0; cp < KIH / 128; cp++) {
#pragma unroll
    for (int i = 0; i < 16; i++) {
      int e = tid + i * 256;
      int k = e & 63, bb = (e >> 6) & 31, h = e >> 11;
      int kg = (2 * cp + h) * 64 + k;
      float v;
      if (C0) {
        if (kg < Hd) v = A1[(long)(bbase + bb) * Hd + kg];
        else v = emb[(long)xs[bb] * Ed + (kg - Hd)];
      } else {
        v = A1[(long)(bbase + bb) * Hd + kg];
      }
      As[h][bb][k] = v;
    }
    __syncthreads();
    int kg0 = (2 * cp + kh) * 64;
    const float* wrp = wr + kg0;
    const float* wzp = wz + kg0;
    const float* wnp = wn + kg0;
#pragma unroll 4
    for (int k = 0; k < 64; k += 4) {
      float4 a4 = *(const float4*)&As[kh][b_][k];
      float4 r4 = *(const float4*)&wrp[k];
      float4 z4 = *(const float4*)&wzp[k];
      float4 n4 = *(const float4*)&wnp[k];
      pr += a4.x * r4.x + a4.y * r4.y + a4.z * r4.z + a4.w * r4.w;
      pz += a4.x * z4.x + a4.y * z4.y + a4.z * z4.z + a4.w * z4.w;
      pin += a4.x * n4.x + a4.y * n4.y + a4.z * n4.z + a4.w * n4.w;
    }
    __syncthreads();
  }
  // hidden-hidden chunks
  const float* vr = &Whh[(long)j * Hd];
  const float* vz = &Whh[(long)(Hd + j) * Hd];
  const float* vn = &Whh[(long)(2 * Hd + j) * Hd];
  for (int cp = 0; cp < Hd / 128; cp++) {
#pragma unroll
    for (int i = 0; i < 16; i++) {
      int e = tid + i * 256;
      int k = e & 63, bb = (e >> 6) & 31, h = e >> 11;
      int kg = (2 * cp + h) * 64 + k;
      As[h][bb][k] = A2[(long)(bbase + bb) * Hd + kg];
    }
    __syncthreads();
    int kg0 = (2 * cp + kh) * 64;
    const float* vrp = vr + kg0;
    const float* vzp = vz + kg0;
    const float* vnp = vn + kg0;
#pragma unroll 4
    for (int k = 0; k < 64; k += 4) {
      float4 a4 = *(const float4*)&As[kh][b_][k];
      float4 r4 = *(const float4*)&vrp[k];
      float4 z4 = *(const float4*)&vzp[k];
      float4 n4 = *(const float4*)&vnp[k];
      pr += a4.x * r4.x + a4.y * r4.y + a4.z * r4.z + a4.w * r4.w;
      pz += a4.x * z4.x + a4.y * z4.y + a4.z * z4.z + a4.w * z4.w;
      phn += a4.x * n4.x + a4.y * n4.y + a4.z * n4.z + a4.w * n4.w;
    }
    __syncthreads();
  }
  // combine K-halves via LDS
  float* ps = (float*)As;  // [8][32][4]
  float* pw = &ps[(s5 * 32 + b_) * 4];
  pw[0] = pr; pw[1] = pz; pw[2] = pin; pw[3] = phn;
  __syncthreads();
  if (s5 < 4) {
    const float* p0 = &ps[(s5 * 32 + b_) * 4];
    const float* p1 = &ps[((s5 + 4) * 32 + b_) * 4];
    float Pr = p0[0] + p1[0], Pz = p0[1] + p1[1];
    float Pin = p0[2] + p1[2], Phn = p0[3] + p1[3];
    int jj = jg * 4 + s5;
    float r = fast_sigmoid(Pr + bih[jj] + bhh[jj]);
    float z = fast_sigmoid(Pz + bih[Hd + jj] + bhh[Hd + jj]);
    float n = fast_tanh(Pin + bih[2 * Hd + jj] + r * (Phn + bhh[2 * Hd + jj]));
    float hp = A2[(long)b * Hd + jj];
    float hn = (1.f - z) * n + z * hp;
    hout[(long)b * Hd + jj] = hn;
    if (!C0) ys[((long)t * Bd + b) * Hd + jj] = hn;
  }
}

__global__ __launch_bounds__(256, 1) void k_decoder(
    const int* __restrict__ x, const float* __restrict__ enc,
    const float* __restrict__ h0_in, const int* __restrict__ vlen,
    const float* __restrict__ emb, const float* __restrict__ Wq,
    const float* __restrict__ wvp, const float* __restrict__ Wih0,
    const float* __restrict__ Whh0, const float* __restrict__ bih0,
    const float* __restrict__ bhh0, const float* __restrict__ Wih1,
    const float* __restrict__ Whh1, const float* __restrict__ bih1,
    const float* __restrict__ bhh1, const float* __restrict__ kp,
    int* bar, float* ctx, float* h0A, float* h0B, float* h1A, float* h1B,
    float* ys) {
  __shared__ __align__(16) float As[2][32][68];
  __shared__ __align__(16) float wvs[Hd];
  __shared__ __align__(16) float h1s[Hd];
  __shared__ __align__(16) float qps[Hd];
  __shared__ float sc[Sd];
  __shared__ float red[16];
  __shared__ int xs[32];
  int blk = blockIdx.x, tid = threadIdx.x;
  int lane = tid & 63, wid = tid >> 6;
  int* arrive = bar;
  int* go = bar + NBLK;
  int ep = 0;

  // init: copy h0 into ping buffers; stage wv in LDS (persists whole kernel)
  if (blk < Bd) {
    wvs[tid] = wvp[tid];
    wvs[tid + 256] = wvp[tid + 256];
    h0A[blk * Hd + tid] = h0_in[blk * Hd + tid];
    h0A[blk * Hd + tid + 256] = h0_in[blk * Hd + tid + 256];
    h1A[blk * Hd + tid] = h0_in[(Bd + blk) * Hd + tid];
    h1A[blk * Hd + tid + 256] = h0_in[(Bd + blk) * Hd + tid + 256];
  }
  gbar(arrive, go, ++ep, blk, tid);

  for (int t = 0; t < Td; t++) {
    const float* h0prev = (t & 1) ? h0B : h0A;
    float* h0next = (t & 1) ? h0A : h0B;
    const float* h1prev = (t & 1) ? h1B : h1A;
    float* h1next = (t & 1) ? h1A : h1B;

    // ---- Phase A: fused qproj + attention, blocks 0..63 (b = blk) ----
    if (blk < Bd) {
      int b = blk;
      h1s[tid] = h1prev[b * Hd + tid];
      h1s[tid + 256] = h1prev[b * Hd + tid + 256];
      __syncthreads();
      float4 hA = *(const float4*)&h1s[lane * 8];
      float4 hB = *(const float4*)&h1s[lane * 8 + 4];
      // qproj: wave `wid` computes rows [wid*128, wid*128+128), 2 per iter
      for (int nn = 0; nn < 128; nn += 2) {
        int n = wid * 128 + nn;
        const float* r0 = &Wq[(long)n * Hd + lane * 8];
        const float* r1 = r0 + Hd;
        float4 w00 = *(const float4*)r0, w01 = *(const float4*)(r0 + 4);
        float4 w10 = *(const float4*)r1, w11 = *(const float4*)(r1 + 4);
        float a0 = hA.x * w00.x + hA.y * w00.y + hA.z * w00.z + hA.w * w00.w +
                   hB.x * w01.x + hB.y * w01.y + hB.z * w01.z + hB.w * w01.w;
        float a1 = hA.x * w10.x + hA.y * w10.y + hA.z * w10.z + hA.w * w10.w +
                   hB.x * w11.x + hB.y * w11.y + hB.z * w11.z + hB.w * w11.w;
#pragma unroll
        for (int off = 1; off < 64; off <<= 1) {
          a0 += __shfl_xor(a0, off);
          a1 += __shfl_xor(a1, off);
        }
        if (lane == 0) {
          qps[n] = a0;
          qps[n + 1] = a1;
        }
      }
      __syncthreads();
      // scores: wave `wid` handles s in [wid*32, wid*32+32)
      float4 qA = *(const float4*)&qps[lane * 8];
      float4 qB = *(const float4*)&qps[lane * 8 + 4];
      float4 vA = *(const float4*)&wvs[lane * 8];
      float4 vB = *(const float4*)&wvs[lane * 8 + 4];
      int vl = vlen[b];
      for (int ss = 0; ss < 32; ss++) {
        int s = wid * 32 + ss;
        const float* kr = &kp[((long)b * Sd + s) * Hd + lane * 8];
        float4 kA = *(const float4*)kr;
        float4 kB = *(const float4*)(kr + 4);
        float acc = vA.x * fast_tanh(qA.x + kA.x) + vA.y * fast_tanh(qA.y + kA.y) +
                    vA.z * fast_tanh(qA.z + kA.z) + vA.w * fast_tanh(qA.w + kA.w) +
                    vB.x * fast_tanh(qB.x + kB.x) + vB.y * fast_tanh(qB.y + kB.y) +
                    vB.z * fast_tanh(qB.z + kB.z) + vB.w * fast_tanh(qB.w + kB.w);
#pragma unroll
        for (int off = 1; off < 64; off <<= 1) acc += __shfl_xor(acc, off);
        if (lane == 0) sc[s] = (s < vl) ? acc : -1e6f;
      }
      __syncthreads();
      // masked softmax over 128 (two waves)
      if (tid < 128) {
        float m = sc[tid];
#pragma unroll
        for (int off = 1; off < 64; off <<= 1) m = fmaxf(m, __shfl_xor(m, off));
        if (lane == 0) red[tid >> 6] = m;
      }
      __syncthreads();
      float gm = fmaxf(red[0], red[1]);
      if (tid < 128) {
        float p = __expf(sc[tid] - gm);
        sc[tid] = p;
        float l = p;
#pragma unroll
        for (int off = 1; off < 64; off <<= 1) l += __shfl_xor(l, off);
        if (lane == 0) red[8 + (tid >> 6)] = l;
      }
      __syncthreads();
      float inv = 1.0f / (red[8] + red[9]);
      if (tid < 128) sc[tid] *= inv;
      __syncthreads();
      // context: thread handles 2 h via float2
      {
        const float* eb = &enc[(long)b * Sd * Hd + tid * 2];
        float ax = 0.f, ay = 0.f, bx = 0.f, by = 0.f;
        for (int s = 0; s < Sd; s += 2) {
          float2 e0 = *(const float2*)&eb[(long)s * Hd];
          float2 e1 = *(const float2*)&eb[(long)(s + 1) * Hd];
          ax += sc[s] * e0.x;
          ay += sc[s] * e0.y;
          bx += sc[s + 1] * e1.x;
          by += sc[s + 1] * e1.y;
        }
        float2 o;
        o.x = ax + bx;
        o.y = ay + by;
        *(float2*)&ctx[(long)b * Hd + tid * 2] = o;
      }
    }
    gbar(arrive, go, ++ep, blk, tid);
    // ---- Phase B: GRU cell 0 (all 256 blocks) ----
    cell_phase<true>(blk, tid, As, xs, ctx, emb, x, t, h0prev, Wih0, Whh0, bih0,
                     bhh0, h0next, nullptr);
    gbar(arrive, go, ++ep, blk, tid);
    // ---- Phase C: GRU cell 1 ----
    cell_phase<false>(blk, tid, As, xs, h0next, nullptr, nullptr, t, h1prev, Wih1,
                      Whh1, bih1, bhh1, h1next, ys);
    gbar(arrive, go, ++ep, blk, tid);
  }
}

extern "C" void kernel_launch(void* const* d_in, const int* in_sizes, int n_in,
                              void* d_out, int out_size, void* d_ws, size_t ws_size,
                              hipStream_t stream) {
  const int* x = (const int*)d_in[0];
  const float* enc = (const float*)d_in[1];
  const float* h0 = (const float*)d_in[2];
  const int* vlen = (const int*)d_in[3];
  const float* emb = (const float*)d_in[4];
  const float* Wq = (const float*)d_in[5];
  const float* Wk = (const float*)d_in[6];
  const float* wv = (const float*)d_in[7];
  const float* W_ih0 = (const float*)d_in[8];
  const float* W_hh0 = (const float*)d_in[9];
  const float* b_ih0 = (const float*)d_in[10];
  const float* b_hh0 = (const float*)d_in[11];
  const float* W_ih1 = (const float*)d_in[12];
  const float* W_hh1 = (const float*)d_in[13];
  const float* b_ih1 = (const float*)d_in[14];
  const float* b_hh1 = (const float*)d_in[15];
  const float* Wd = (const float*)d_in[16];
  const float* bd = (const float*)d_in[17];
  float* out = (float*)d_out;

  int* bar = (int*)d_ws;                      // 512 ints (2KB)
  float* w = (float*)((char*)d_ws + 2048);
  float* kp = w;                              // B*S*H
  float* ctx = kp + (long)Bd * Sd * Hd;       // B*H
  float* h0A = ctx + Bd * Hd;
  float* h0B = h0A + Bd * Hd;
  float* h1A = h0B + Bd * Hd;
  float* h1B = h1A + Bd * Hd;
  float* ys = h1B + Bd * Hd;                  // T*B*H

  // zero the barrier region every call (replay-deterministic)
  hipMemsetAsync(bar, 0, 2048, stream);

  // k_proj = enc @ Wk^T : M=8192, N=512, K=512
  k_gemm_abt<false, false><<<dim3(128, 8), 256, 0, stream>>>(enc, Wk, nullptr, kp,
                                                             Bd * Sd, Hd, Hd);
  // fused 64-step decoder (plain launch + software grid barrier)
  k_decoder<<<NBLK, 256, 0, stream>>>(x, enc, h0, vlen, emb, Wq, wv, W_ih0, W_hh0,
                                      b_ih0, b_hh0, W_ih1, W_hh1, b_ih1, b_hh1, kp,
                                      bar, ctx, h0A, h0B, h1A, h1B, ys);
  // logits: ys(T*B,H) @ Wd^T + bd, out[b,t,v]
  k_gemm_abt<true, true><<<dim3(64, 157), 256, 0, stream>>>(ys, Wd, bd, out,
                                                            Td * Bd, Vd, Hd);
}

// Round 4
// 18565.617 us; speedup vs baseline: 1.7015x; 1.7015x over previous
//
#include <hip/hip_runtime.h>
#include <hip/hip_bf16.h>

#define Bd 64
#define Td 64
#define Sd 128
#define Hd 512
#define Ed 256
#define Vd 10000
#define NBLK 256

__device__ __forceinline__ float fast_tanh(float x) {
  float e = __expf(-2.0f * fabsf(x));
  float r = (1.0f - e) / (1.0f + e);
  return copysignf(r, x);
}
__device__ __forceinline__ float fast_sigmoid(float x) {
  return 1.0f / (1.0f + __expf(-x));
}
__device__ __forceinline__ float bf2f(unsigned short u) {
  return __uint_as_float(((unsigned int)u) << 16);
}

// software grid barrier: arrive[NBLK] slots + go flag, monotonic epoch
__device__ __forceinline__ void gbar(int* arrive, int* go, int ep, int blk, int tid) {
  __syncthreads();
  if (tid == 0) {
    __threadfence();
    __hip_atomic_store(&arrive[blk], ep, __ATOMIC_RELEASE, __HIP_MEMORY_SCOPE_AGENT);
  }
  if (blk == 0) {
    while (__hip_atomic_load(&arrive[tid], __ATOMIC_ACQUIRE,
                             __HIP_MEMORY_SCOPE_AGENT) < ep) {
      __builtin_amdgcn_s_sleep(1);
    }
    __syncthreads();
    if (tid == 0)
      __hip_atomic_store(go, ep, __ATOMIC_RELEASE, __HIP_MEMORY_SCOPE_AGENT);
  }
  if (tid == 0) {
    while (__hip_atomic_load(go, __ATOMIC_ACQUIRE, __HIP_MEMORY_SCOPE_AGENT) < ep) {
      __builtin_amdgcn_s_sleep(1);
    }
  }
  __syncthreads();
}

// C[M,N] = A[M,K] @ W[N,K]^T (+bias). SWAP: out row m=(t*64+b) -> (b*T+t).
// OB: store bf16 (ushort) instead of f32.
template <bool SWAP, bool BIAS, bool OB>
__global__ void k_gemm_abt(const float* __restrict__ A, const float* __restrict__ W,
                           const float* __restrict__ bias, void* __restrict__ Cv,
                           int M, int N, int K) {
  __shared__ __align__(16) float As[16][64];
  __shared__ __align__(16) float Ws[16][64];
  int m0 = blockIdx.x * 64, n0 = blockIdx.y * 64;
  int tid = threadIdx.x;
  int tx = tid & 15, ty = tid >> 4;
  float acc[4][4] = {};
  for (int k0 = 0; k0 < K; k0 += 16) {
#pragma unroll
    for (int i = 0; i < 4; i++) {
      int e = tid + i * 256;
      int r = e >> 4, c = e & 15;
      As[c][r] = A[(long)(m0 + r) * K + k0 + c];
    }
#pragma unroll
    for (int i = 0; i < 4; i++) {
      int e = tid + i * 256;
      int r = e >> 4, c = e & 15;
      int n = n0 + r;
      Ws[c][r] = (n < N) ? W[(long)n * K + k0 + c] : 0.0f;
    }
    __syncthreads();
#pragma unroll
    for (int k = 0; k < 16; k++) {
      float a_[4], w_[4];
#pragma unroll
      for (int i = 0; i < 4; i++) a_[i] = As[k][ty * 4 + i];
#pragma unroll
      for (int j = 0; j < 4; j++) w_[j] = Ws[k][tx * 4 + j];
#pragma unroll
      for (int i = 0; i < 4; i++)
#pragma unroll
        for (int j = 0; j < 4; j++) acc[i][j] += a_[i] * w_[j];
    }
    __syncthreads();
  }
#pragma unroll
  for (int i = 0; i < 4; i++) {
    int m = m0 + ty * 4 + i;
#pragma unroll
    for (int j = 0; j < 4; j++) {
      int n = n0 + tx * 4 + j;
      if (n < N) {
        float v = acc[i][j];
        if (BIAS) v += bias[n];
        long idx;
        if (SWAP) {
          int t_ = m >> 6, b_ = m & 63;
          idx = ((long)(b_ * Td + t_)) * N + n;
        } else {
          idx = (long)m * N + n;
        }
        if (OB) {
          __hip_bfloat16 h = __float2bfloat16(v);
          ((unsigned short*)Cv)[idx] = *(unsigned short*)&h;
        } else {
          ((float*)Cv)[idx] = v;
        }
      }
    }
  }
}

// embT[t][e][b] = bf16(emb[x[b][t]][e])
__global__ void k_embT(const int* __restrict__ x, const float* __restrict__ emb,
                       unsigned short* __restrict__ embT) {
  int t = blockIdx.x;
  int b = threadIdx.x & 63, el = threadIdx.x >> 6;
  int row = x[b * Td + t];
  for (int e0 = 0; e0 < Ed; e0 += 4) {
    int e = e0 + el;
    float v = emb[(long)row * Ed + e];
    __hip_bfloat16 h = __float2bfloat16(v);
    embT[((long)t * Ed + e) * 64 + b] = *(unsigned short*)&h;
  }
}

// GRU cell phase: block owns 2 output channels j0,j1; wave = K-quarter; lane = b.
// Weights read wave-uniform (scalar path), activations from transposed [K][64].
template <bool C0>
__device__ void cell_phase(int blk, int tid, int t, const float* __restrict__ aT,
                           const unsigned short* __restrict__ embT,
                           const float* __restrict__ hT, const float* __restrict__ Wih,
                           const float* __restrict__ Whh, const float* __restrict__ bih,
                           const float* __restrict__ bhh, float* __restrict__ houtT,
                           float* __restrict__ ys, float (*ps)[64][8]) {
  const int KA = C0 ? (Hd + Ed) : Hd;
  int lane = tid & 63;
  int w = __builtin_amdgcn_readfirstlane(threadIdx.x >> 6);
  int j0 = blk * 2, j1 = j0 + 1;
  const float* ir0 = Wih + (size_t)j0 * KA;
  const float* iz0 = Wih + (size_t)(Hd + j0) * KA;
  const float* in0 = Wih + (size_t)(2 * Hd + j0) * KA;
  const float* ir1 = Wih + (size_t)j1 * KA;
  const float* iz1 = Wih + (size_t)(Hd + j1) * KA;
  const float* in1 = Wih + (size_t)(2 * Hd + j1) * KA;
  float pr0 = 0, pz0 = 0, pn0 = 0, ph0 = 0;
  float pr1 = 0, pz1 = 0, pn1 = 0, ph1 = 0;
  int kb = w * (KA / 4), ke = kb + KA / 4;
#pragma unroll 4
  for (int k = kb; k < ke; ++k) {
    float a;
    if (C0) {
      a = (k < Hd) ? aT[k * 64 + lane]
                   : bf2f(embT[((long)(t << 8) + (k - Hd)) * 64 + lane]);
    } else {
      a = aT[k * 64 + lane];
    }
    pr0 += a * ir0[k];
    pz0 += a * iz0[k];
    pn0 += a * in0[k];
    pr1 += a * ir1[k];
    pz1 += a * iz1[k];
    pn1 += a * in1[k];
  }
  const float* hr0 = Whh + (size_t)j0 * Hd;
  const float* hz0 = Whh + (size_t)(Hd + j0) * Hd;
  const float* hn0 = Whh + (size_t)(2 * Hd + j0) * Hd;
  const float* hr1 = Whh + (size_t)j1 * Hd;
  const float* hz1 = Whh + (size_t)(Hd + j1) * Hd;
  const float* hn1 = Whh + (size_t)(2 * Hd + j1) * Hd;
  int kb2 = w * 128, ke2 = kb2 + 128;
#pragma unroll 4
  for (int k = kb2; k < ke2; ++k) {
    float a = hT[k * 64 + lane];
    pr0 += a * hr0[k];
    pz0 += a * hz0[k];
    ph0 += a * hn0[k];
    pr1 += a * hr1[k];
    pz1 += a * hz1[k];
    ph1 += a * hn1[k];
  }
  ps[w][lane][0] = pr0;
  ps[w][lane][1] = pz0;
  ps[w][lane][2] = pn0;
  ps[w][lane][3] = ph0;
  ps[w][lane][4] = pr1;
  ps[w][lane][5] = pz1;
  ps[w][lane][6] = pn1;
  ps[w][lane][7] = ph1;
  __syncthreads();
  if (tid < 128) {
    int jl = tid >> 6, b = tid & 63;
    float sr = 0, sz = 0, sn = 0, sh = 0;
#pragma unroll
    for (int q = 0; q < 4; q++) {
      sr += ps[q][b][jl * 4 + 0];
      sz += ps[q][b][jl * 4 + 1];
      sn += ps[q][b][jl * 4 + 2];
      sh += ps[q][b][jl * 4 + 3];
    }
    int j = blk * 2 + jl;
    float r = fast_sigmoid(sr + bih[j] + bhh[j]);
    float z = fast_sigmoid(sz + bih[Hd + j] + bhh[Hd + j]);
    float n = fast_tanh(sn + bih[2 * Hd + j] + r * (sh + bhh[2 * Hd + j]));
    float hp = hT[j * 64 + b];
    float hn2 = (1.f - z) * n + z * hp;
    houtT[j * 64 + b] = hn2;
    if (!C0) ys[((size_t)t * 64 + b) * Hd + j] = hn2;
  }
  __syncthreads();
}

__global__ __launch_bounds__(256, 1) void k_decoder(
    const int* __restrict__ x, const float* __restrict__ enc,
    const float* __restrict__ h0_in, const int* __restrict__ vlen,
    const float* __restrict__ Wq, const float* __restrict__ wvp,
    const float* __restrict__ Wih0, const float* __restrict__ Whh0,
    const float* __restrict__ bih0, const float* __restrict__ bhh0,
    const float* __restrict__ Wih1, const float* __restrict__ Whh1,
    const float* __restrict__ bih1, const float* __restrict__ bhh1,
    const unsigned short* __restrict__ kpbf, const unsigned short* __restrict__ embT,
    int* bar, float* qpT, float* ctxT, float* h0TA, float* h0TB, float* h1TA,
    float* h1TB, float* ys) {
  __shared__ float ps[4][64][8];
  __shared__ __align__(16) float qps[Hd];
  __shared__ __align__(16) float wvs[Hd];
  __shared__ float sc[Sd];
  __shared__ float red[16];
  int blk = blockIdx.x, tid = threadIdx.x;
  int lane = tid & 63;
  int* arrive = bar;
  int* go = bar + NBLK;
  int ep = 0;

  // init: transpose h0 into h0TA/h1TA (blocks 0..63, b = blk)
  if (blk < Bd) {
    int b = blk;
#pragma unroll
    for (int i = 0; i < 2; i++) {
      int k = tid + i * 256;
      h0TA[k * 64 + b] = h0_in[(0 * Bd + b) * Hd + k];
      h1TA[k * 64 + b] = h0_in[(1 * Bd + b) * Hd + k];
    }
  }
  gbar(arrive, go, ++ep, blk, tid);

  for (int t = 0; t < Td; t++) {
    const float* h0prev = (t & 1) ? h0TB : h0TA;
    float* h0next = (t & 1) ? h0TA : h0TB;
    const float* h1prev = (t & 1) ? h1TB : h1TA;
    float* h1next = (t & 1) ? h1TA : h1TB;

    // ---- P0: qproj distributed: block computes rows r0,r1 of qp ----
    {
      int w = __builtin_amdgcn_readfirstlane(threadIdx.x >> 6);
      int r0 = blk * 2, r1 = r0 + 1;
      const float* q0 = Wq + (size_t)r0 * Hd;
      const float* q1 = Wq + (size_t)r1 * Hd;
      float a0 = 0, a1 = 0;
      int kb = w * 128, ke = kb + 128;
#pragma unroll 4
      for (int k = kb; k < ke; ++k) {
        float a = h1prev[k * 64 + lane];
        a0 += a * q0[k];
        a1 += a * q1[k];
      }
      ps[w][lane][0] = a0;
      ps[w][lane][1] = a1;
      __syncthreads();
      if (tid < 128) {
        int rl = tid >> 6, b = tid & 63;
        float s = ps[0][b][rl] + ps[1][b][rl] + ps[2][b][rl] + ps[3][b][rl];
        qpT[(blk * 2 + rl) * 64 + b] = s;
      }
    }
    gbar(arrive, go, ++ep, blk, tid);

    // ---- P1: attention (blocks 0..63, b = blk) ----
    if (blk < Bd) {
      int b = blk;
      int w = tid >> 6;
      qps[tid] = qpT[tid * 64 + b];
      qps[tid + 256] = qpT[(tid + 256) * 64 + b];
      wvs[tid] = wvp[tid];
      wvs[tid + 256] = wvp[tid + 256];
      __syncthreads();
      float qv[8], vv[8];
#pragma unroll
      for (int i = 0; i < 8; i++) {
        qv[i] = qps[lane * 8 + i];
        vv[i] = wvs[lane * 8 + i];
      }
      int vl = vlen[b];
      for (int ss = 0; ss < 32; ss++) {
        int s = w * 32 + ss;
        const unsigned short* kr = kpbf + ((size_t)b * Sd + s) * Hd + lane * 8;
        uint4 kw = *(const uint4*)kr;
        float acc;
        {
          float f0 = __uint_as_float(kw.x << 16);
          float f1 = __uint_as_float(kw.x & 0xffff0000u);
          float f2 = __uint_as_float(kw.y << 16);
          float f3 = __uint_as_float(kw.y & 0xffff0000u);
          float f4 = __uint_as_float(kw.z << 16);
          float f5 = __uint_as_float(kw.z & 0xffff0000u);
          float f6 = __uint_as_float(kw.w << 16);
          float f7 = __uint_as_float(kw.w & 0xffff0000u);
          acc = vv[0] * fast_tanh(qv[0] + f0) + vv[1] * fast_tanh(qv[1] + f1) +
                vv[2] * fast_tanh(qv[2] + f2) + vv[3] * fast_tanh(qv[3] + f3) +
                vv[4] * fast_tanh(qv[4] + f4) + vv[5] * fast_tanh(qv[5] + f5) +
                vv[6] * fast_tanh(qv[6] + f6) + vv[7] * fast_tanh(qv[7] + f7);
        }
#pragma unroll
        for (int off = 1; off < 64; off <<= 1) acc += __shfl_xor(acc, off);
        if (lane == 0) sc[s] = (s < vl) ? acc : -1e6f;
      }
      __syncthreads();
      if (tid < 128) {
        float m = sc[tid];
#pragma unroll
        for (int off = 1; off < 64; off <<= 1) m = fmaxf(m, __shfl_xor(m, off));
        if (lane == 0) red[tid >> 6] = m;
      }
      __syncthreads();
      float gm = fmaxf(red[0], red[1]);
      if (tid < 128) {
        float p = __expf(sc[tid] - gm);
        sc[tid] = p;
        float l = p;
#pragma unroll
        for (int off = 1; off < 64; off <<= 1) l += __shfl_xor(l, off);
        if (lane == 0) red[8 + (tid >> 6)] = l;
      }
      __syncthreads();
      float inv = 1.0f / (red[8] + red[9]);
      if (tid < 128) sc[tid] *= inv;
      __syncthreads();
      {
        int h2 = tid * 2;
        const float* eb = &enc[(size_t)b * Sd * Hd + h2];
        float ax = 0.f, ay = 0.f;
        for (int s = 0; s < Sd; s++) {
          float2 e0 = *(const float2*)&eb[(size_t)s * Hd];
          float w0 = sc[s];
          ax += w0 * e0.x;
          ay += w0 * e0.y;
        }
        ctxT[h2 * 64 + b] = ax;
        ctxT[(h2 + 1) * 64 + b] = ay;
      }
    }
    gbar(arrive, go, ++ep, blk, tid);

    // ---- P2: GRU cell 0 ----
    cell_phase<true>(blk, tid, t, ctxT, embT, h0prev, Wih0, Whh0, bih0, bhh0,
                     h0next, nullptr, ps);
    gbar(arrive, go, ++ep, blk, tid);

    // ---- P3: GRU cell 1 ----
    cell_phase<false>(blk, tid, t, h0next, nullptr, h1prev, Wih1, Whh1, bih1, bhh1,
                      h1next, ys, ps);
    gbar(arrive, go, ++ep, blk, tid);
  }
}

extern "C" void kernel_launch(void* const* d_in, const int* in_sizes, int n_in,
                              void* d_out, int out_size, void* d_ws, size_t ws_size,
                              hipStream_t stream) {
  const int* x = (const int*)d_in[0];
  const float* enc = (const float*)d_in[1];
  const float* h0 = (const float*)d_in[2];
  const int* vlen = (const int*)d_in[3];
  const float* emb = (const float*)d_in[4];
  const float* Wq = (const float*)d_in[5];
  const float* Wk = (const float*)d_in[6];
  const float* wv = (const float*)d_in[7];
  const float* W_ih0 = (const float*)d_in[8];
  const float* W_hh0 = (const float*)d_in[9];
  const float* b_ih0 = (const float*)d_in[10];
  const float* b_hh0 = (const float*)d_in[11];
  const float* W_ih1 = (const float*)d_in[12];
  const float* W_hh1 = (const float*)d_in[13];
  const float* b_ih1 = (const float*)d_in[14];
  const float* b_hh1 = (const float*)d_in[15];
  const float* Wd = (const float*)d_in[16];
  const float* bd = (const float*)d_in[17];
  float* out = (float*)d_out;

  char* p = (char*)d_ws;
  int* bar = (int*)p;                      // 2 KB
  p += 2048;
  unsigned short* kpbf = (unsigned short*)p;  // B*S*H bf16 = 8.39 MB
  p += (size_t)Bd * Sd * Hd * 2;
  unsigned short* embT = (unsigned short*)p;  // T*E*B bf16 = 2.1 MB
  p += (size_t)Td * Ed * Bd * 2;
  float* qpT = (float*)p;   p += (size_t)Hd * Bd * 4;
  float* ctxT = (float*)p;  p += (size_t)Hd * Bd * 4;
  float* h0TA = (float*)p;  p += (size_t)Hd * Bd * 4;
  float* h0TB = (float*)p;  p += (size_t)Hd * Bd * 4;
  float* h1TA = (float*)p;  p += (size_t)Hd * Bd * 4;
  float* h1TB = (float*)p;  p += (size_t)Hd * Bd * 4;
  float* ys = (float*)p;    // T*B*H f32 = 8.39 MB

  hipMemsetAsync(bar, 0, 2048, stream);

  // kp = enc @ Wk^T -> bf16 : M=8192, N=512, K=512
  k_gemm_abt<false, false, true><<<dim3(128, 8), 256, 0, stream>>>(
      enc, Wk, nullptr, kpbf, Bd * Sd, Hd, Hd);
  // embT gather+transpose+bf16
  k_embT<<<Td, 256, 0, stream>>>(x, emb, embT);
  // fused 64-step decoder
  k_decoder<<<NBLK, 256, 0, stream>>>(x, enc, h0, vlen, Wq, wv, W_ih0, W_hh0,
                                      b_ih0, b_hh0, W_ih1, W_hh1, b_ih1, b_hh1,
                                      kpbf, embT, bar, qpT, ctxT, h0TA, h0TB,
                                      h1TA, h1TB, ys);
  // logits: ys(T*B,H) @ Wd^T + bd, out[b,t,v]
  k_gemm_abt<true, true, false><<<dim3(64, 157), 256, 0, stream>>>(
      ys, Wd, bd, out, Td * Bd, Vd, Hd);
}

// Round 6
// 17598.749 us; speedup vs baseline: 1.7950x; 1.0549x over previous
//
#include <hip/hip_runtime.h>
#include <hip/hip_bf16.h>

#define Bd 64
#define Td 64
#define Sd 128
#define Hd 512
#define Ed 256
#define Vd 10000
#define NBLK 256

// LDS weight offsets (floats)
#define W0IH 0      // 6*768
#define W0HH 4608   // 6*512
#define W1IH 7680   // 6*512
#define W1HH 10752  // 6*512
#define WTOT 13824

__device__ __forceinline__ float fast_tanh(float x) {
  float e = __expf(-2.0f * fabsf(x));
  float r = (1.0f - e) / (1.0f + e);
  return copysignf(r, x);
}
__device__ __forceinline__ float fast_sigmoid(float x) {
  return 1.0f / (1.0f + __expf(-x));
}

// software grid barrier: arrive[NBLK] slots + go flag, monotonic epoch
__device__ __forceinline__ void gbar(int* arrive, int* go, int ep, int blk, int tid) {
  __syncthreads();
  if (tid == 0) {
    __threadfence();
    __hip_atomic_store(&arrive[blk], ep, __ATOMIC_RELEASE, __HIP_MEMORY_SCOPE_AGENT);
  }
  if (blk == 0) {
    if (tid < NBLK) {
      while (__hip_atomic_load(&arrive[tid], __ATOMIC_ACQUIRE,
                               __HIP_MEMORY_SCOPE_AGENT) < ep) {
        __builtin_amdgcn_s_sleep(1);
      }
    }
    __syncthreads();
    if (tid == 0)
      __hip_atomic_store(go, ep, __ATOMIC_RELEASE, __HIP_MEMORY_SCOPE_AGENT);
  }
  if (tid == 0) {
    while (__hip_atomic_load(go, __ATOMIC_ACQUIRE, __HIP_MEMORY_SCOPE_AGENT) < ep) {
      __builtin_amdgcn_s_sleep(1);
    }
  }
  __syncthreads();
}

// C[M,N] = A[M,K] @ W[N,K]^T (+bias). SWAP: out row m=(t*64+b) -> (b*T+t).
// OB: store bf16 (ushort) instead of f32.
template <bool SWAP, bool BIAS, bool OB>
__global__ void k_gemm_abt(const float* __restrict__ A, const float* __restrict__ W,
                           const float* __restrict__ bias, void* __restrict__ Cv,
                           int M, int N, int K) {
  __shared__ __align__(16) float As[16][64];
  __shared__ __align__(16) float Ws[16][64];
  int m0 = blockIdx.x * 64, n0 = blockIdx.y * 64;
  int tid = threadIdx.x;
  int tx = tid & 15, ty = tid >> 4;
  float acc[4][4] = {};
  for (int k0 = 0; k0 < K; k0 += 16) {
#pragma unroll
    for (int i = 0; i < 4; i++) {
      int e = tid + i * 256;
      int r = e >> 4, c = e & 15;
      As[c][r] = A[(long)(m0 + r) * K + k0 + c];
    }
#pragma unroll
    for (int i = 0; i < 4; i++) {
      int e = tid + i * 256;
      int r = e >> 4, c = e & 15;
      int n = n0 + r;
      Ws[c][r] = (n < N) ? W[(long)n * K + k0 + c] : 0.0f;
    }
    __syncthreads();
#pragma unroll
    for (int k = 0; k < 16; k++) {
      float a_[4], w_[4];
#pragma unroll
      for (int i = 0; i < 4; i++) a_[i] = As[k][ty * 4 + i];
#pragma unroll
      for (int j = 0; j < 4; j++) w_[j] = Ws[k][tx * 4 + j];
#pragma unroll
      for (int i = 0; i < 4; i++)
#pragma unroll
        for (int j = 0; j < 4; j++) acc[i][j] += a_[i] * w_[j];
    }
    __syncthreads();
  }
#pragma unroll
  for (int i = 0; i < 4; i++) {
    int m = m0 + ty * 4 + i;
#pragma unroll
    for (int j = 0; j < 4; j++) {
      int n = n0 + tx * 4 + j;
      if (n < N) {
        float v = acc[i][j];
        if (BIAS) v += bias[n];
        long idx;
        if (SWAP) {
          int t_ = m >> 6, b_ = m & 63;
          idx = ((long)(b_ * Td + t_)) * N + n;
        } else {
          idx = (long)m * N + n;
        }
        if (OB) {
          __hip_bfloat16 h = __float2bfloat16(v);
          ((unsigned short*)Cv)[idx] = *(unsigned short*)&h;
        } else {
          ((float*)Cv)[idx] = v;
        }
      }
    }
  }
}

// embTf[t][e][b] = emb[x[b][t]][e]  (f32)
__global__ void k_embT(const int* __restrict__ x, const float* __restrict__ emb,
                       float* __restrict__ embTf) {
  __shared__ int rows[64];
  int t = blockIdx.x;
  if (threadIdx.x < 64) rows[threadIdx.x] = x[threadIdx.x * Td + t];
  __syncthreads();
  int e = threadIdx.x;  // 256 threads = 256 e
  for (int b = 0; b < 64; b++) {
    embTf[((long)t * Ed + e) * 64 + b] = emb[(long)rows[b] * Ed + e];
  }
}

// GRU cell phase, 16 waves. Waves 0-5: ih row-dots (k<512 of aT); waves 6-11: hh
// row-dots over hT; waves 12-14 (cell0 only): emb part (k 512..768). Row rr =
// gate*2 + jl, j = 2*blk + jl. Combine + nonlinearity by threads 0-127.
template <bool C0>
__device__ __forceinline__ void cell_phase(
    int blk, int tid, int t, const float* __restrict__ aT,
    const float* __restrict__ embTf, const float* __restrict__ hT,
    const float* wIH, const float* wHH, const float* __restrict__ bih,
    const float* __restrict__ bhh, float* __restrict__ houtT,
    float* __restrict__ ys, float* scratch) {
  int lane = tid & 63;
  int w = tid >> 6;
  const int RIH = C0 ? 768 : 512;
  float* ps = scratch;         // [12][64]
  float* psE = scratch + 768;  // [6][64]
  if (w < 6) {
    const float* wr = wIH + w * RIH;
    float acc = 0.f;
#pragma unroll 8
    for (int k = 0; k < 512; k++) acc += aT[k * 64 + lane] * wr[k];
    ps[w * 64 + lane] = acc;
  } else if (w < 12) {
    const float* vr = wHH + (w - 6) * 512;
    float acc = 0.f;
#pragma unroll 8
    for (int k = 0; k < 512; k++) acc += hT[k * 64 + lane] * vr[k];
    ps[w * 64 + lane] = acc;
  } else if (C0 && w < 15) {
    int r0 = (w - 12) * 2;
    const float* w0 = wIH + r0 * 768 + 512;
    const float* w1 = wIH + (r0 + 1) * 768 + 512;
    const float* ef = embTf + (size_t)t * Ed * 64;
    float a0 = 0.f, a1 = 0.f;
#pragma unroll 8
    for (int e = 0; e < 256; e++) {
      float a = ef[e * 64 + lane];
      a0 += a * w0[e];
      a1 += a * w1[e];
    }
    psE[r0 * 64 + lane] = a0;
    psE[(r0 + 1) * 64 + lane] = a1;
  }
  __syncthreads();
  if (tid < 128) {
    int jl = tid >> 6, b = tid & 63;
    float ir = ps[(0 + jl) * 64 + b];
    float iz = ps[(2 + jl) * 64 + b];
    float in = ps[(4 + jl) * 64 + b];
    if (C0) {
      ir += psE[(0 + jl) * 64 + b];
      iz += psE[(2 + jl) * 64 + b];
      in += psE[(4 + jl) * 64 + b];
    }
    float hr = ps[(6 + jl) * 64 + b];
    float hz = ps[(8 + jl) * 64 + b];
    float hn_ = ps[(10 + jl) * 64 + b];
    int j = blk * 2 + jl;
    float r = fast_sigmoid(ir + hr + bih[j] + bhh[j]);
    float z = fast_sigmoid(iz + hz + bih[Hd + j] + bhh[Hd + j]);
    float n = fast_tanh(in + bih[2 * Hd + j] + r * (hn_ + bhh[2 * Hd + j]));
    float hp = hT[j * 64 + b];
    float out = (1.f - z) * n + z * hp;
    houtT[j * 64 + b] = out;
    if (!C0) ys[((size_t)t * 64 + b) * Hd + j] = out;
  }
}

__global__ __launch_bounds__(1024, 1) void k_decoder(
    const float* __restrict__ enc, const float* __restrict__ h0_in,
    const int* __restrict__ vlen, const float* __restrict__ Wq,
    const float* __restrict__ wvp, const float* __restrict__ Wih0,
    const float* __restrict__ Whh0, const float* __restrict__ bih0,
    const float* __restrict__ bhh0, const float* __restrict__ Wih1,
    const float* __restrict__ Whh1, const float* __restrict__ bih1,
    const float* __restrict__ bhh1, const unsigned short* __restrict__ kpbf,
    const float* __restrict__ embTf, int* bar, float* qpT, float* ctxT,
    float* h0TA, float* h0TB, float* h1TA, float* h1TB, float* ys) {
  __shared__ __align__(16) float wLDS[WTOT];   // 55296 B
  __shared__ __align__(16) float scratch[1280];  // 5120 B union
  int blk = blockIdx.x, tid = threadIdx.x;
  int lane = tid & 63;
  int w = tid >> 6;
  int* arrive = bar;
  int* go = bar + NBLK;
  int ep = 0;

  // ---- one-time: weights -> LDS ----
  {
    int j0 = blk * 2;
#pragma unroll
    for (int rr = 0; rr < 6; rr++) {
      int g = rr >> 1, jl = rr & 1;
      int row = g * Hd + j0 + jl;
      const float* s0 = Wih0 + (size_t)row * 768;
      for (int k = tid; k < 768; k += 1024) wLDS[W0IH + rr * 768 + k] = s0[k];
      const float* s1 = Whh0 + (size_t)row * Hd;
      for (int k = tid; k < Hd; k += 1024) wLDS[W0HH + rr * 512 + k] = s1[k];
      const float* s2 = Wih1 + (size_t)row * Hd;
      for (int k = tid; k < Hd; k += 1024) wLDS[W1IH + rr * 512 + k] = s2[k];
      const float* s3 = Whh1 + (size_t)row * Hd;
      for (int k = tid; k < Hd; k += 1024) wLDS[W1HH + rr * 512 + k] = s3[k];
    }
  }
  // wv -> registers (per-lane slice, constant all steps)
  float wvr[8];
#pragma unroll
  for (int i = 0; i < 8; i++) wvr[i] = wvp[lane * 8 + i];

  // init: transpose h0 into ping buffers (blocks 0..63)
  if (blk < Bd) {
    int b = blk;
    for (int k = tid; k < Hd; k += 1024) {
      h0TA[k * 64 + b] = h0_in[(0 * Bd + b) * Hd + k];
      h1TA[k * 64 + b] = h0_in[(1 * Bd + b) * Hd + k];
    }
  }
  gbar(arrive, go, ++ep, blk, tid);

  for (int t = 0; t < Td; t++) {
    const float* h0prev = (t & 1) ? h0TB : h0TA;
    float* h0next = (t & 1) ? h0TA : h0TB;
    const float* h1prev = (t & 1) ? h1TB : h1TA;
    float* h1next = (t & 1) ? h1TA : h1TB;

    // ---- P0: qproj, all 256 blocks: rows 2blk, 2blk+1; K split 8x64 ----
    {
      int rl = w >> 3, ks = w & 7;
      const float* qrow = Wq + (size_t)(blk * 2 + rl) * Hd + ks * 64;
      const float* hp = h1prev + ks * 64 * 64;
      float acc = 0.f;
#pragma unroll 8
      for (int kk = 0; kk < 64; kk++) acc += hp[kk * 64 + lane] * qrow[kk];
      scratch[w * 64 + lane] = acc;
      __syncthreads();
      if (tid < 128) {
        int rl2 = tid >> 6, b = tid & 63;
        float s = 0.f;
#pragma unroll
        for (int q = 0; q < 8; q++) s += scratch[(rl2 * 8 + q) * 64 + b];
        qpT[(blk * 2 + rl2) * 64 + b] = s;
      }
    }
    gbar(arrive, go, ++ep, blk, tid);

    // ---- P1: attention (blocks 0..63, b = blk) ----
    if (blk < Bd) {
      int b = blk;
      float* sc = scratch;          // [128]
      float* red = scratch + 128;   // [16]
      float qv[8];
#pragma unroll
      for (int i = 0; i < 8; i++) qv[i] = qpT[(lane * 8 + i) * 64 + b];
      int vl = vlen[b];
      // scores: wave w -> s = w*8 + si
#pragma unroll
      for (int si = 0; si < 8; si++) {
        int s = w * 8 + si;
        const unsigned short* kr = kpbf + ((size_t)b * Sd + s) * Hd + lane * 8;
        uint4 kw = *(const uint4*)kr;
        float f0 = __uint_as_float(kw.x << 16);
        float f1 = __uint_as_float(kw.x & 0xffff0000u);
        float f2 = __uint_as_float(kw.y << 16);
        float f3 = __uint_as_float(kw.y & 0xffff0000u);
        float f4 = __uint_as_float(kw.z << 16);
        float f5 = __uint_as_float(kw.z & 0xffff0000u);
        float f6 = __uint_as_float(kw.w << 16);
        float f7 = __uint_as_float(kw.w & 0xffff0000u);
        float acc = wvr[0] * fast_tanh(qv[0] + f0) + wvr[1] * fast_tanh(qv[1] + f1) +
                    wvr[2] * fast_tanh(qv[2] + f2) + wvr[3] * fast_tanh(qv[3] + f3) +
                    wvr[4] * fast_tanh(qv[4] + f4) + wvr[5] * fast_tanh(qv[5] + f5) +
                    wvr[6] * fast_tanh(qv[6] + f6) + wvr[7] * fast_tanh(qv[7] + f7);
#pragma unroll
        for (int off = 1; off < 64; off <<= 1) acc += __shfl_xor(acc, off);
        if (lane == 0) sc[s] = (s < vl) ? acc : -1e6f;
      }
      __syncthreads();
      if (tid < 128) {
        float m = sc[tid];
#pragma unroll
        for (int off = 1; off < 64; off <<= 1) m = fmaxf(m, __shfl_xor(m, off));
        if (lane == 0) red[tid >> 6] = m;
      }
      __syncthreads();
      float gm = fmaxf(red[0], red[1]);
      if (tid < 128) {
        float p = __expf(sc[tid] - gm);
        sc[tid] = p;
        float l = p;
#pragma unroll
        for (int off = 1; off < 64; off <<= 1) l += __shfl_xor(l, off);
        if (lane == 0) red[8 + (tid >> 6)] = l;
      }
      __syncthreads();
      float inv = 1.0f / (red[8] + red[9]);
      if (tid < 128) sc[tid] *= inv;
      __syncthreads();
      // context: threads 0..511, h = tid
      if (tid < Hd) {
        const float* eb = enc + (size_t)b * Sd * Hd + tid;
        float acc = 0.f;
#pragma unroll 8
        for (int s = 0; s < Sd; s++) acc += sc[s] * eb[(size_t)s * Hd];
        ctxT[tid * 64 + b] = acc;
      }
    }
    gbar(arrive, go, ++ep, blk, tid);

    // ---- P2: GRU cell 0 ----
    cell_phase<true>(blk, tid, t, ctxT, embTf, h0prev, wLDS + W0IH, wLDS + W0HH,
                     bih0, bhh0, h0next, nullptr, scratch);
    gbar(arrive, go, ++ep, blk, tid);

    // ---- P3: GRU cell 1 ----
    cell_phase<false>(blk, tid, t, h0next, nullptr, h1prev, wLDS + W1IH,
                      wLDS + W1HH, bih1, bhh1, h1next, ys, scratch);
    gbar(arrive, go, ++ep, blk, tid);
  }
}

extern "C" void kernel_launch(void* const* d_in, const int* in_sizes, int n_in,
                              void* d_out, int out_size, void* d_ws, size_t ws_size,
                              hipStream_t stream) {
  const int* x = (const int*)d_in[0];
  const float* enc = (const float*)d_in[1];
  const float* h0 = (const float*)d_in[2];
  const int* vlen = (const int*)d_in[3];
  const float* emb = (const float*)d_in[4];
  const float* Wq = (const float*)d_in[5];
  const float* Wk = (const float*)d_in[6];
  const float* wv = (const float*)d_in[7];
  const float* W_ih0 = (const float*)d_in[8];
  const float* W_hh0 = (const float*)d_in[9];
  const float* b_ih0 = (const float*)d_in[10];
  const float* b_hh0 = (const float*)d_in[11];
  const float* W_ih1 = (const float*)d_in[12];
  const float* W_hh1 = (const float*)d_in[13];
  const float* b_ih1 = (const float*)d_in[14];
  const float* b_hh1 = (const float*)d_in[15];
  const float* Wd = (const float*)d_in[16];
  const float* bd = (const float*)d_in[17];
  float* out = (float*)d_out;

  char* p = (char*)d_ws;
  int* bar = (int*)p;
  p += 2048;
  unsigned short* kpbf = (unsigned short*)p;  // B*S*H bf16
  p += (size_t)Bd * Sd * Hd * 2;
  float* embTf = (float*)p;  // T*E*B f32
  p += (size_t)Td * Ed * Bd * 4;
  float* qpT = (float*)p;   p += (size_t)Hd * Bd * 4;
  float* ctxT = (float*)p;  p += (size_t)Hd * Bd * 4;
  float* h0TA = (float*)p;  p += (size_t)Hd * Bd * 4;
  float* h0TB = (float*)p;  p += (size_t)Hd * Bd * 4;
  float* h1TA = (float*)p;  p += (size_t)Hd * Bd * 4;
  float* h1TB = (float*)p;  p += (size_t)Hd * Bd * 4;
  float* ys = (float*)p;    // T*B*H f32

  hipMemsetAsync(bar, 0, 2048, stream);

  // kp = enc @ Wk^T -> bf16
  k_gemm_abt<false, false, true><<<dim3(128, 8), 256, 0, stream>>>(
      enc, Wk, nullptr, kpbf, Bd * Sd, Hd, Hd);
  // embTf gather+transpose (f32)
  k_embT<<<Td, 256, 0, stream>>>(x, emb, embTf);
  // fused 64-step decoder
  k_decoder<<<NBLK, 1024, 0, stream>>>(enc, h0, vlen, Wq, wv, W_ih0, W_hh0, b_ih0,
                                       b_hh0, W_ih1, W_hh1, b_ih1, b_hh1, kpbf,
                                       embTf, bar, qpT, ctxT, h0TA, h0TB, h1TA,
                                       h1TB, ys);
  // logits: ys(T*B,H) @ Wd^T + bd, out[b,t,v]
  k_gemm_abt<true, true, false><<<dim3(64, 157), 256, 0, stream>>>(
      ys, Wd, bd, out, Td * Bd, Vd, Hd);
}

// Round 7
// 17251.462 us; speedup vs baseline: 1.8311x; 1.0201x over previous
//
#include <hip/hip_runtime.h>
#include <hip/hip_bf16.h>

#define Bd 64
#define Td 64
#define Sd 128
#define Hd 512
#define Ed 256
#define Vd 10000
#define NBLK 256

// LDS weight offsets (floats)
#define W0IH 0      // 6*768
#define W0HH 4608   // 6*512
#define W1IH 7680   // 6*512
#define W1HH 10752  // 6*512
#define WTOT 13824

__device__ __forceinline__ float fast_tanh(float x) {
  float e = __expf(-2.0f * fabsf(x));
  float r = (1.0f - e) / (1.0f + e);
  return copysignf(r, x);
}
__device__ __forceinline__ float fast_sigmoid(float x) {
  return 1.0f / (1.0f + __expf(-x));
}
__device__ __forceinline__ float bf2f(unsigned short u) {
  return __uint_as_float(((unsigned int)u) << 16);
}

// software grid barrier: arrive[NBLK] slots + go flag, monotonic epoch
__device__ __forceinline__ void gbar(int* arrive, int* go, int ep, int blk, int tid) {
  __syncthreads();
  if (tid == 0) {
    __threadfence();
    __hip_atomic_store(&arrive[blk], ep, __ATOMIC_RELEASE, __HIP_MEMORY_SCOPE_AGENT);
  }
  if (blk == 0) {
    if (tid < NBLK) {
      while (__hip_atomic_load(&arrive[tid], __ATOMIC_ACQUIRE,
                               __HIP_MEMORY_SCOPE_AGENT) < ep) {
        __builtin_amdgcn_s_sleep(1);
      }
    }
    __syncthreads();
    if (tid == 0)
      __hip_atomic_store(go, ep, __ATOMIC_RELEASE, __HIP_MEMORY_SCOPE_AGENT);
  }
  if (tid == 0) {
    while (__hip_atomic_load(go, __ATOMIC_ACQUIRE, __HIP_MEMORY_SCOPE_AGENT) < ep) {
      __builtin_amdgcn_s_sleep(1);
    }
  }
  __syncthreads();
}

// C[M,N] = A[M,K] @ W[N,K]^T (+bias). SWAP: out row m=(t*64+b) -> (b*T+t).
// OB: store bf16 (ushort) instead of f32.
template <bool SWAP, bool BIAS, bool OB>
__global__ void k_gemm_abt(const float* __restrict__ A, const float* __restrict__ W,
                           const float* __restrict__ bias, void* __restrict__ Cv,
                           int M, int N, int K) {
  __shared__ __align__(16) float As[16][64];
  __shared__ __align__(16) float Ws[16][64];
  int m0 = blockIdx.x * 64, n0 = blockIdx.y * 64;
  int tid = threadIdx.x;
  int tx = tid & 15, ty = tid >> 4;
  float acc[4][4] = {};
  for (int k0 = 0; k0 < K; k0 += 16) {
#pragma unroll
    for (int i = 0; i < 4; i++) {
      int e = tid + i * 256;
      int r = e >> 4, c = e & 15;
      As[c][r] = A[(long)(m0 + r) * K + k0 + c];
    }
#pragma unroll
    for (int i = 0; i < 4; i++) {
      int e = tid + i * 256;
      int r = e >> 4, c = e & 15;
      int n = n0 + r;
      Ws[c][r] = (n < N) ? W[(long)n * K + k0 + c] : 0.0f;
    }
    __syncthreads();
#pragma unroll
    for (int k = 0; k < 16; k++) {
      float a_[4], w_[4];
#pragma unroll
      for (int i = 0; i < 4; i++) a_[i] = As[k][ty * 4 + i];
#pragma unroll
      for (int j = 0; j < 4; j++) w_[j] = Ws[k][tx * 4 + j];
#pragma unroll
      for (int i = 0; i < 4; i++)
#pragma unroll
        for (int j = 0; j < 4; j++) acc[i][j] += a_[i] * w_[j];
    }
    __syncthreads();
  }
#pragma unroll
  for (int i = 0; i < 4; i++) {
    int m = m0 + ty * 4 + i;
#pragma unroll
    for (int j = 0; j < 4; j++) {
      int n = n0 + tx * 4 + j;
      if (n < N) {
        float v = acc[i][j];
        if (BIAS) v += bias[n];
        long idx;
        if (SWAP) {
          int t_ = m >> 6, b_ = m & 63;
          idx = ((long)(b_ * Td + t_)) * N + n;
        } else {
          idx = (long)m * N + n;
        }
        if (OB) {
          __hip_bfloat16 h = __float2bfloat16(v);
          ((unsigned short*)Cv)[idx] = *(unsigned short*)&h;
        } else {
          ((float*)Cv)[idx] = v;
        }
      }
    }
  }
}

// elementwise f32 -> bf16 copy
__global__ void k_tobf(const float* __restrict__ src, unsigned short* __restrict__ dst,
                       long n) {
  long i = (long)blockIdx.x * 1024 + threadIdx.x;
  if (i < n) {
    __hip_bfloat16 h = __float2bfloat16(src[i]);
    dst[i] = *(unsigned short*)&h;
  }
}

// embTf[t][e][b] = emb[x[b][t]][e]  (f32)
__global__ void k_embT(const int* __restrict__ x, const float* __restrict__ emb,
                       float* __restrict__ embTf) {
  __shared__ int rows[64];
  int t = blockIdx.x;
  if (threadIdx.x < 64) rows[threadIdx.x] = x[threadIdx.x * Td + t];
  __syncthreads();
  int e = threadIdx.x;  // 256 threads = 256 e
  for (int b = 0; b < 64; b++) {
    embTf[((long)t * Ed + e) * 64 + b] = emb[(long)rows[b] * Ed + e];
  }
}

// GRU cell phase, 16 waves. Waves 0-5: ih row-dots (k<512 of aT); waves 6-11: hh
// row-dots over hT; waves 12-14 (cell0 only): emb part (k 512..768). Row rr =
// gate*2 + jl, j = 2*blk + jl. Combine + nonlinearity by threads 0-127.
template <bool C0>
__device__ __forceinline__ void cell_phase(
    int blk, int tid, int t, const float* __restrict__ aT,
    const float* __restrict__ embTf, const float* __restrict__ hT,
    const float* wIH, const float* wHH, const float* __restrict__ bih,
    const float* __restrict__ bhh, float* __restrict__ houtT,
    float* __restrict__ ys, float* scratch) {
  int lane = tid & 63;
  int w = tid >> 6;
  const int RIH = C0 ? 768 : 512;
  float* ps = scratch;         // [12][64]
  float* psE = scratch + 768;  // [6][64]
  if (w < 6) {
    const float* wr = wIH + w * RIH;
    float acc = 0.f;
#pragma unroll 8
    for (int k = 0; k < 512; k++) acc += aT[k * 64 + lane] * wr[k];
    ps[w * 64 + lane] = acc;
  } else if (w < 12) {
    const float* vr = wHH + (w - 6) * 512;
    float acc = 0.f;
#pragma unroll 8
    for (int k = 0; k < 512; k++) acc += hT[k * 64 + lane] * vr[k];
    ps[w * 64 + lane] = acc;
  } else if (C0 && w < 15) {
    int r0 = (w - 12) * 2;
    const float* w0 = wIH + r0 * 768 + 512;
    const float* w1 = wIH + (r0 + 1) * 768 + 512;
    const float* ef = embTf + (size_t)t * Ed * 64;
    float a0 = 0.f, a1 = 0.f;
#pragma unroll 8
    for (int e = 0; e < 256; e++) {
      float a = ef[e * 64 + lane];
      a0 += a * w0[e];
      a1 += a * w1[e];
    }
    psE[r0 * 64 + lane] = a0;
    psE[(r0 + 1) * 64 + lane] = a1;
  }
  __syncthreads();
  if (tid < 128) {
    int jl = tid >> 6, b = tid & 63;
    float ir = ps[(0 + jl) * 64 + b];
    float iz = ps[(2 + jl) * 64 + b];
    float in = ps[(4 + jl) * 64 + b];
    if (C0) {
      ir += psE[(0 + jl) * 64 + b];
      iz += psE[(2 + jl) * 64 + b];
      in += psE[(4 + jl) * 64 + b];
    }
    float hr = ps[(6 + jl) * 64 + b];
    float hz = ps[(8 + jl) * 64 + b];
    float hn_ = ps[(10 + jl) * 64 + b];
    int j = blk * 2 + jl;
    float r = fast_sigmoid(ir + hr + bih[j] + bhh[j]);
    float z = fast_sigmoid(iz + hz + bih[Hd + j] + bhh[Hd + j]);
    float n = fast_tanh(in + bih[2 * Hd + j] + r * (hn_ + bhh[2 * Hd + j]));
    float hp = hT[j * 64 + b];
    float out = (1.f - z) * n + z * hp;
    houtT[j * 64 + b] = out;
    if (!C0) ys[((size_t)t * 64 + b) * Hd + j] = out;
  }
}

__global__ __launch_bounds__(1024, 1) void k_decoder(
    const unsigned short* __restrict__ encbf, const float* __restrict__ h0_in,
    const int* __restrict__ vlen, const float* __restrict__ Wq,
    const float* __restrict__ wvp, const float* __restrict__ Wih0,
    const float* __restrict__ Whh0, const float* __restrict__ bih0,
    const float* __restrict__ bhh0, const float* __restrict__ Wih1,
    const float* __restrict__ Whh1, const float* __restrict__ bih1,
    const float* __restrict__ bhh1, const unsigned short* __restrict__ kpbf,
    const float* __restrict__ embTf, int* bar, float* qpT, float* ctxT,
    float* h0TA, float* h0TB, float* h1TA, float* h1TB, float* ys) {
  __shared__ __align__(16) float wLDS[WTOT];   // 55296 B
  __shared__ __align__(16) float scratch[1280];  // 5120 B union
  int blk = blockIdx.x, tid = threadIdx.x;
  int lane = tid & 63;
  int w = tid >> 6;
  int* arrive = bar;
  int* go = bar + NBLK;
  int ep = 0;

  // ---- one-time: weights -> LDS ----
  {
    int j0 = blk * 2;
#pragma unroll
    for (int rr = 0; rr < 6; rr++) {
      int g = rr >> 1, jl = rr & 1;
      int row = g * Hd + j0 + jl;
      const float* s0 = Wih0 + (size_t)row * 768;
      for (int k = tid; k < 768; k += 1024) wLDS[W0IH + rr * 768 + k] = s0[k];
      const float* s1 = Whh0 + (size_t)row * Hd;
      for (int k = tid; k < Hd; k += 1024) wLDS[W0HH + rr * 512 + k] = s1[k];
      const float* s2 = Wih1 + (size_t)row * Hd;
      for (int k = tid; k < Hd; k += 1024) wLDS[W1IH + rr * 512 + k] = s2[k];
      const float* s3 = Whh1 + (size_t)row * Hd;
      for (int k = tid; k < Hd; k += 1024) wLDS[W1HH + rr * 512 + k] = s3[k];
    }
  }
  // wv -> registers (per-lane slice, constant all steps)
  float wvr[8];
#pragma unroll
  for (int i = 0; i < 8; i++) wvr[i] = wvp[lane * 8 + i];

  // init: transpose h0 into ping buffers (blocks 0..63)
  if (blk < Bd) {
    int b = blk;
    for (int k = tid; k < Hd; k += 1024) {
      h0TA[k * 64 + b] = h0_in[(0 * Bd + b) * Hd + k];
      h1TA[k * 64 + b] = h0_in[(1 * Bd + b) * Hd + k];
    }
  }
  gbar(arrive, go, ++ep, blk, tid);

  for (int t = 0; t < Td; t++) {
    const float* h0prev = (t & 1) ? h0TB : h0TA;
    float* h0next = (t & 1) ? h0TA : h0TB;
    const float* h1prev = (t & 1) ? h1TB : h1TA;
    float* h1next = (t & 1) ? h1TA : h1TB;

    // ---- P0: qproj, all 256 blocks: rows 2blk, 2blk+1; K split 8x64 ----
    {
      int rl = w >> 3, ks = w & 7;
      const float* qrow = Wq + (size_t)(blk * 2 + rl) * Hd + ks * 64;
      const float* hp = h1prev + ks * 64 * 64;
      float acc = 0.f;
#pragma unroll 8
      for (int kk = 0; kk < 64; kk++) acc += hp[kk * 64 + lane] * qrow[kk];
      scratch[w * 64 + lane] = acc;
      __syncthreads();
      if (tid < 128) {
        int rl2 = tid >> 6, b = tid & 63;
        float s = 0.f;
#pragma unroll
        for (int q = 0; q < 8; q++) s += scratch[(rl2 * 8 + q) * 64 + b];
        qpT[(blk * 2 + rl2) * 64 + b] = s;
      }
    }
    gbar(arrive, go, ++ep, blk, tid);

    // ---- P1: attention (blocks 0..63, b = blk) ----
    if (blk < Bd) {
      int b = blk;
      float* sc = scratch;          // [128]
      float* red = scratch + 128;   // [16]
      float qv[8];
#pragma unroll
      for (int i = 0; i < 8; i++) qv[i] = qpT[(lane * 8 + i) * 64 + b];
      int vl = vlen[b];
      // scores: wave w -> s = w*8 + si
#pragma unroll
      for (int si = 0; si < 8; si++) {
        int s = w * 8 + si;
        const unsigned short* kr = kpbf + ((size_t)b * Sd + s) * Hd + lane * 8;
        uint4 kw = *(const uint4*)kr;
        float f0 = __uint_as_float(kw.x << 16);
        float f1 = __uint_as_float(kw.x & 0xffff0000u);
        float f2 = __uint_as_float(kw.y << 16);
        float f3 = __uint_as_float(kw.y & 0xffff0000u);
        float f4 = __uint_as_float(kw.z << 16);
        float f5 = __uint_as_float(kw.z & 0xffff0000u);
        float f6 = __uint_as_float(kw.w << 16);
        float f7 = __uint_as_float(kw.w & 0xffff0000u);
        float acc = wvr[0] * fast_tanh(qv[0] + f0) + wvr[1] * fast_tanh(qv[1] + f1) +
                    wvr[2] * fast_tanh(qv[2] + f2) + wvr[3] * fast_tanh(qv[3] + f3) +
                    wvr[4] * fast_tanh(qv[4] + f4) + wvr[5] * fast_tanh(qv[5] + f5) +
                    wvr[6] * fast_tanh(qv[6] + f6) + wvr[7] * fast_tanh(qv[7] + f7);
#pragma unroll
        for (int off = 1; off < 64; off <<= 1) acc += __shfl_xor(acc, off);
        if (lane == 0) sc[s] = (s < vl) ? acc : -1e6f;
      }
      __syncthreads();
      if (tid < 128) {
        float m = sc[tid];
#pragma unroll
        for (int off = 1; off < 64; off <<= 1) m = fmaxf(m, __shfl_xor(m, off));
        if (lane == 0) red[tid >> 6] = m;
      }
      __syncthreads();
      float gm = fmaxf(red[0], red[1]);
      if (tid < 128) {
        float p = __expf(sc[tid] - gm);
        sc[tid] = p;
        float l = p;
#pragma unroll
        for (int off = 1; off < 64; off <<= 1) l += __shfl_xor(l, off);
        if (lane == 0) red[8 + (tid >> 6)] = l;
      }
      __syncthreads();
      float inv = 1.0f / (red[8] + red[9]);
      if (tid < 128) sc[tid] *= inv;
      __syncthreads();
      // context: 1024 threads: h = tid&511, s-half = tid>>9; bf16 enc
      {
        int h = tid & 511, sh = tid >> 9;
        const unsigned short* eb =
            encbf + (size_t)b * Sd * Hd + (size_t)(sh * 64) * Hd + h;
        float acc = 0.f;
#pragma unroll 8
        for (int s = 0; s < 64; s++) acc += sc[sh * 64 + s] * bf2f(eb[(size_t)s * Hd]);
        if (sh == 1) scratch[640 + h] = acc;
        __syncthreads();
        if (tid < 512) ctxT[tid * 64 + b] = acc + scratch[640 + tid];
      }
    }
    gbar(arrive, go, ++ep, blk, tid);

    // ---- P2: GRU cell 0 ----
    cell_phase<true>(blk, tid, t, ctxT, embTf, h0prev, wLDS + W0IH, wLDS + W0HH,
                     bih0, bhh0, h0next, nullptr, scratch);
    gbar(arrive, go, ++ep, blk, tid);

    // ---- P3: GRU cell 1 ----
    cell_phase<false>(blk, tid, t, h0next, nullptr, h1prev, wLDS + W1IH,
                      wLDS + W1HH, bih1, bhh1, h1next, ys, scratch);
    gbar(arrive, go, ++ep, blk, tid);
  }
}

extern "C" void kernel_launch(void* const* d_in, const int* in_sizes, int n_in,
                              void* d_out, int out_size, void* d_ws, size_t ws_size,
                              hipStream_t stream) {
  const int* x = (const int*)d_in[0];
  const float* enc = (const float*)d_in[1];
  const float* h0 = (const float*)d_in[2];
  const int* vlen = (const int*)d_in[3];
  const float* emb = (const float*)d_in[4];
  const float* Wq = (const float*)d_in[5];
  const float* Wk = (const float*)d_in[6];
  const float* wv = (const float*)d_in[7];
  const float* W_ih0 = (const float*)d_in[8];
  const float* W_hh0 = (const float*)d_in[9];
  const float* b_ih0 = (const float*)d_in[10];
  const float* b_hh0 = (const float*)d_in[11];
  const float* W_ih1 = (const float*)d_in[12];
  const float* W_hh1 = (const float*)d_in[13];
  const float* b_ih1 = (const float*)d_in[14];
  const float* b_hh1 = (const float*)d_in[15];
  const float* Wd = (const float*)d_in[16];
  const float* bd = (const float*)d_in[17];
  float* out = (float*)d_out;

  char* p = (char*)d_ws;
  int* bar = (int*)p;
  p += 2048;
  unsigned short* kpbf = (unsigned short*)p;  // B*S*H bf16
  p += (size_t)Bd * Sd * Hd * 2;
  unsigned short* encbf = (unsigned short*)p;  // B*S*H bf16
  p += (size_t)Bd * Sd * Hd * 2;
  float* embTf = (float*)p;  // T*E*B f32
  p += (size_t)Td * Ed * Bd * 4;
  float* qpT = (float*)p;   p += (size_t)Hd * Bd * 4;
  float* ctxT = (float*)p;  p += (size_t)Hd * Bd * 4;
  float* h0TA = (float*)p;  p += (size_t)Hd * Bd * 4;
  float* h0TB = (float*)p;  p += (size_t)Hd * Bd * 4;
  float* h1TA = (float*)p;  p += (size_t)Hd * Bd * 4;
  float* h1TB = (float*)p;  p += (size_t)Hd * Bd * 4;
  float* ys = (float*)p;    // T*B*H f32

  hipMemsetAsync(bar, 0, 2048, stream);

  // kp = enc @ Wk^T -> bf16
  k_gemm_abt<false, false, true><<<dim3(128, 8), 256, 0, stream>>>(
      enc, Wk, nullptr, kpbf, Bd * Sd, Hd, Hd);
  // enc -> bf16 copy
  long nenc = (long)Bd * Sd * Hd;
  k_tobf<<<(nenc + 1023) / 1024, 1024, 0, stream>>>(enc, encbf, nenc);
  // embTf gather+transpose (f32)
  k_embT<<<Td, 256, 0, stream>>>(x, emb, embTf);
  // fused 64-step decoder
  k_decoder<<<NBLK, 1024, 0, stream>>>(encbf, h0, vlen, Wq, wv, W_ih0, W_hh0,
                                       b_ih0, b_hh0, W_ih1, W_hh1, b_ih1, b_hh1,
                                       kpbf, embTf, bar, qpT, ctxT, h0TA, h0TB,
                                       h1TA, h1TB, ys);
  // logits: ys(T*B,H) @ Wd^T + bd, out[b,t,v]
  k_gemm_abt<true, true, false><<<dim3(64, 157), 256, 0, stream>>>(
      ys, Wd, bd, out, Td * Bd, Vd, Hd);
}

// Round 8
// 6941.330 us; speedup vs baseline: 4.5509x; 2.4853x over previous
//
#include <hip/hip_runtime.h>
#include <hip/hip_bf16.h>

#define Bd 64
#define Td 64
#define Sd 128
#define Hd 512
#define Ed 256
#define Vd 10000
#define NBLK 256

// LDS weight offsets (floats)
#define W0IH 0      // 6*768
#define W0HH 4608   // 6*512
#define W1IH 7680   // 6*512
#define W1HH 10752  // 6*512
#define WTOT 13824

__device__ __forceinline__ float fast_tanh(float x) {
  float e = __expf(-2.0f * fabsf(x));
  float r = (1.0f - e) / (1.0f + e);
  return copysignf(r, x);
}
__device__ __forceinline__ float fast_sigmoid(float x) {
  return 1.0f / (1.0f + __expf(-x));
}
__device__ __forceinline__ float bf2f(unsigned short u) {
  return __uint_as_float(((unsigned int)u) << 16);
}

// software grid barrier: RELAXED spins (no per-poll cache ops!) + exactly one
// release fence (writeback) before arrive and one acquire fence (invalidate)
// at exit. Agent-scope relaxed atomics bypass L2 (coherent point) so polling
// does not invalidate caches — the r2-r7 version acquire-polled, nuking the
// XCD L2 every iteration from every idle block.
__device__ __forceinline__ void gbar(int* arrive, int* go, int ep, int blk, int tid) {
  __syncthreads();
  if (tid == 0) {
    __builtin_amdgcn_fence(__ATOMIC_RELEASE, "agent");  // wbl2: flush produced data
    __hip_atomic_store(&arrive[blk], ep, __ATOMIC_RELAXED, __HIP_MEMORY_SCOPE_AGENT);
  }
  if (blk == 0) {
    if (tid < NBLK) {
      while (__hip_atomic_load(&arrive[tid], __ATOMIC_RELAXED,
                               __HIP_MEMORY_SCOPE_AGENT) < ep) {
        __builtin_amdgcn_s_sleep(1);
      }
    }
    __syncthreads();
    if (tid == 0)
      __hip_atomic_store(go, ep, __ATOMIC_RELAXED, __HIP_MEMORY_SCOPE_AGENT);
  }
  if (tid == 0) {
    while (__hip_atomic_load(go, __ATOMIC_RELAXED, __HIP_MEMORY_SCOPE_AGENT) < ep) {
      __builtin_amdgcn_s_sleep(1);
    }
    __builtin_amdgcn_fence(__ATOMIC_ACQUIRE, "agent");  // single L2 invalidate
  }
  __syncthreads();
}

// C[M,N] = A[M,K] @ W[N,K]^T (+bias). SWAP: out row m=(t*64+b) -> (b*T+t).
// OB: store bf16 (ushort) instead of f32.
template <bool SWAP, bool BIAS, bool OB>
__global__ void k_gemm_abt(const float* __restrict__ A, const float* __restrict__ W,
                           const float* __restrict__ bias, void* __restrict__ Cv,
                           int M, int N, int K) {
  __shared__ __align__(16) float As[16][64];
  __shared__ __align__(16) float Ws[16][64];
  int m0 = blockIdx.x * 64, n0 = blockIdx.y * 64;
  int tid = threadIdx.x;
  int tx = tid & 15, ty = tid >> 4;
  float acc[4][4] = {};
  for (int k0 = 0; k0 < K; k0 += 16) {
#pragma unroll
    for (int i = 0; i < 4; i++) {
      int e = tid + i * 256;
      int r = e >> 4, c = e & 15;
      As[c][r] = A[(long)(m0 + r) * K + k0 + c];
    }
#pragma unroll
    for (int i = 0; i < 4; i++) {
      int e = tid + i * 256;
      int r = e >> 4, c = e & 15;
      int n = n0 + r;
      Ws[c][r] = (n < N) ? W[(long)n * K + k0 + c] : 0.0f;
    }
    __syncthreads();
#pragma unroll
    for (int k = 0; k < 16; k++) {
      float a_[4], w_[4];
#pragma unroll
      for (int i = 0; i < 4; i++) a_[i] = As[k][ty * 4 + i];
#pragma unroll
      for (int j = 0; j < 4; j++) w_[j] = Ws[k][tx * 4 + j];
#pragma unroll
      for (int i = 0; i < 4; i++)
#pragma unroll
        for (int j = 0; j < 4; j++) acc[i][j] += a_[i] * w_[j];
    }
    __syncthreads();
  }
#pragma unroll
  for (int i = 0; i < 4; i++) {
    int m = m0 + ty * 4 + i;
#pragma unroll
    for (int j = 0; j < 4; j++) {
      int n = n0 + tx * 4 + j;
      if (n < N) {
        float v = acc[i][j];
        if (BIAS) v += bias[n];
        long idx;
        if (SWAP) {
          int t_ = m >> 6, b_ = m & 63;
          idx = ((long)(b_ * Td + t_)) * N + n;
        } else {
          idx = (long)m * N + n;
        }
        if (OB) {
          __hip_bfloat16 h = __float2bfloat16(v);
          ((unsigned short*)Cv)[idx] = *(unsigned short*)&h;
        } else {
          ((float*)Cv)[idx] = v;
        }
      }
    }
  }
}

// elementwise f32 -> bf16 copy
__global__ void k_tobf(const float* __restrict__ src, unsigned short* __restrict__ dst,
                       long n) {
  long i = (long)blockIdx.x * 1024 + threadIdx.x;
  if (i < n) {
    __hip_bfloat16 h = __float2bfloat16(src[i]);
    dst[i] = *(unsigned short*)&h;
  }
}

// embTf[t][e][b] = emb[x[b][t]][e]  (f32)
__global__ void k_embT(const int* __restrict__ x, const float* __restrict__ emb,
                       float* __restrict__ embTf) {
  __shared__ int rows[64];
  int t = blockIdx.x;
  if (threadIdx.x < 64) rows[threadIdx.x] = x[threadIdx.x * Td + t];
  __syncthreads();
  int e = threadIdx.x;  // 256 threads = 256 e
  for (int b = 0; b < 64; b++) {
    embTf[((long)t * Ed + e) * 64 + b] = emb[(long)rows[b] * Ed + e];
  }
}

// GRU cell phase, 16 waves. Waves 0-5: ih row-dots (k<512 of aT); waves 6-11: hh
// row-dots over hT; waves 12-14 (cell0 only): emb part (k 512..768). Row rr =
// gate*2 + jl, j = 2*blk + jl. Combine + nonlinearity by threads 0-127.
template <bool C0>
__device__ __forceinline__ void cell_phase(
    int blk, int tid, int t, const float* __restrict__ aT,
    const float* __restrict__ embTf, const float* __restrict__ hT,
    const float* wIH, const float* wHH, const float* __restrict__ bih,
    const float* __restrict__ bhh, float* __restrict__ houtT,
    float* __restrict__ ys, float* scratch) {
  int lane = tid & 63;
  int w = tid >> 6;
  const int RIH = C0 ? 768 : 512;
  float* ps = scratch;         // [12][64]
  float* psE = scratch + 768;  // [6][64]
  if (w < 6) {
    const float* wr = wIH + w * RIH;
    float acc = 0.f;
#pragma unroll 8
    for (int k = 0; k < 512; k++) acc += aT[k * 64 + lane] * wr[k];
    ps[w * 64 + lane] = acc;
  } else if (w < 12) {
    const float* vr = wHH + (w - 6) * 512;
    float acc = 0.f;
#pragma unroll 8
    for (int k = 0; k < 512; k++) acc += hT[k * 64 + lane] * vr[k];
    ps[w * 64 + lane] = acc;
  } else if (C0 && w < 15) {
    int r0 = (w - 12) * 2;
    const float* w0 = wIH + r0 * 768 + 512;
    const float* w1 = wIH + (r0 + 1) * 768 + 512;
    const float* ef = embTf + (size_t)t * Ed * 64;
    float a0 = 0.f, a1 = 0.f;
#pragma unroll 8
    for (int e = 0; e < 256; e++) {
      float a = ef[e * 64 + lane];
      a0 += a * w0[e];
      a1 += a * w1[e];
    }
    psE[r0 * 64 + lane] = a0;
    psE[(r0 + 1) * 64 + lane] = a1;
  }
  __syncthreads();
  if (tid < 128) {
    int jl = tid >> 6, b = tid & 63;
    float ir = ps[(0 + jl) * 64 + b];
    float iz = ps[(2 + jl) * 64 + b];
    float in = ps[(4 + jl) * 64 + b];
    if (C0) {
      ir += psE[(0 + jl) * 64 + b];
      iz += psE[(2 + jl) * 64 + b];
      in += psE[(4 + jl) * 64 + b];
    }
    float hr = ps[(6 + jl) * 64 + b];
    float hz = ps[(8 + jl) * 64 + b];
    float hn_ = ps[(10 + jl) * 64 + b];
    int j = blk * 2 + jl;
    float r = fast_sigmoid(ir + hr + bih[j] + bhh[j]);
    float z = fast_sigmoid(iz + hz + bih[Hd + j] + bhh[Hd + j]);
    float n = fast_tanh(in + bih[2 * Hd + j] + r * (hn_ + bhh[2 * Hd + j]));
    float hp = hT[j * 64 + b];
    float out = (1.f - z) * n + z * hp;
    houtT[j * 64 + b] = out;
    if (!C0) ys[((size_t)t * 64 + b) * Hd + j] = out;
  }
}

__global__ __launch_bounds__(1024, 1) void k_decoder(
    const unsigned short* __restrict__ encbf, const float* __restrict__ h0_in,
    const int* __restrict__ vlen, const float* __restrict__ Wq,
    const float* __restrict__ wvp, const float* __restrict__ Wih0,
    const float* __restrict__ Whh0, const float* __restrict__ bih0,
    const float* __restrict__ bhh0, const float* __restrict__ Wih1,
    const float* __restrict__ Whh1, const float* __restrict__ bih1,
    const float* __restrict__ bhh1, const unsigned short* __restrict__ kpbf,
    const float* __restrict__ embTf, int* bar, float* qpT, float* ctxT,
    float* h0TA, float* h0TB, float* h1TA, float* h1TB, float* ys) {
  __shared__ __align__(16) float wLDS[WTOT];   // 55296 B
  __shared__ __align__(16) float scratch[1280];  // 5120 B union
  int blk = blockIdx.x, tid = threadIdx.x;
  int lane = tid & 63;
  int w = tid >> 6;
  int* arrive = bar;
  int* go = bar + NBLK;
  int ep = 0;

  // ---- one-time: weights -> LDS ----
  {
    int j0 = blk * 2;
#pragma unroll
    for (int rr = 0; rr < 6; rr++) {
      int g = rr >> 1, jl = rr & 1;
      int row = g * Hd + j0 + jl;
      const float* s0 = Wih0 + (size_t)row * 768;
      for (int k = tid; k < 768; k += 1024) wLDS[W0IH + rr * 768 + k] = s0[k];
      const float* s1 = Whh0 + (size_t)row * Hd;
      for (int k = tid; k < Hd; k += 1024) wLDS[W0HH + rr * 512 + k] = s1[k];
      const float* s2 = Wih1 + (size_t)row * Hd;
      for (int k = tid; k < Hd; k += 1024) wLDS[W1IH + rr * 512 + k] = s2[k];
      const float* s3 = Whh1 + (size_t)row * Hd;
      for (int k = tid; k < Hd; k += 1024) wLDS[W1HH + rr * 512 + k] = s3[k];
    }
  }
  // wv -> registers (per-lane slice, constant all steps)
  float wvr[8];
#pragma unroll
  for (int i = 0; i < 8; i++) wvr[i] = wvp[lane * 8 + i];

  // init: transpose h0 into ping buffers (blocks 0..63)
  if (blk < Bd) {
    int b = blk;
    for (int k = tid; k < Hd; k += 1024) {
      h0TA[k * 64 + b] = h0_in[(0 * Bd + b) * Hd + k];
      h1TA[k * 64 + b] = h0_in[(1 * Bd + b) * Hd + k];
    }
  }
  gbar(arrive, go, ++ep, blk, tid);

  for (int t = 0; t < Td; t++) {
    const float* h0prev = (t & 1) ? h0TB : h0TA;
    float* h0next = (t & 1) ? h0TA : h0TB;
    const float* h1prev = (t & 1) ? h1TB : h1TA;
    float* h1next = (t & 1) ? h1TA : h1TB;

    // ---- P0: qproj, all 256 blocks: rows 2blk, 2blk+1; K split 8x64 ----
    {
      int rl = w >> 3, ks = w & 7;
      const float* qrow = Wq + (size_t)(blk * 2 + rl) * Hd + ks * 64;
      const float* hp = h1prev + ks * 64 * 64;
      float acc = 0.f;
#pragma unroll 8
      for (int kk = 0; kk < 64; kk++) acc += hp[kk * 64 + lane] * qrow[kk];
      scratch[w * 64 + lane] = acc;
      __syncthreads();
      if (tid < 128) {
        int rl2 = tid >> 6, b = tid & 63;
        float s = 0.f;
#pragma unroll
        for (int q = 0; q < 8; q++) s += scratch[(rl2 * 8 + q) * 64 + b];
        qpT[(blk * 2 + rl2) * 64 + b] = s;
      }
    }
    gbar(arrive, go, ++ep, blk, tid);

    // ---- P1: attention (blocks 0..63, b = blk) ----
    if (blk < Bd) {
      int b = blk;
      float* sc = scratch;          // [128]
      float* red = scratch + 128;   // [16]
      float qv[8];
#pragma unroll
      for (int i = 0; i < 8; i++) qv[i] = qpT[(lane * 8 + i) * 64 + b];
      int vl = vlen[b];
      // scores: wave w -> s = w*8 + si
#pragma unroll
      for (int si = 0; si < 8; si++) {
        int s = w * 8 + si;
        const unsigned short* kr = kpbf + ((size_t)b * Sd + s) * Hd + lane * 8;
        uint4 kw = *(const uint4*)kr;
        float f0 = __uint_as_float(kw.x << 16);
        float f1 = __uint_as_float(kw.x & 0xffff0000u);
        float f2 = __uint_as_float(kw.y << 16);
        float f3 = __uint_as_float(kw.y & 0xffff0000u);
        float f4 = __uint_as_float(kw.z << 16);
        float f5 = __uint_as_float(kw.z & 0xffff0000u);
        float f6 = __uint_as_float(kw.w << 16);
        float f7 = __uint_as_float(kw.w & 0xffff0000u);
        float acc = wvr[0] * fast_tanh(qv[0] + f0) + wvr[1] * fast_tanh(qv[1] + f1) +
                    wvr[2] * fast_tanh(qv[2] + f2) + wvr[3] * fast_tanh(qv[3] + f3) +
                    wvr[4] * fast_tanh(qv[4] + f4) + wvr[5] * fast_tanh(qv[5] + f5) +
                    wvr[6] * fast_tanh(qv[6] + f6) + wvr[7] * fast_tanh(qv[7] + f7);
#pragma unroll
        for (int off = 1; off < 64; off <<= 1) acc += __shfl_xor(acc, off);
        if (lane == 0) sc[s] = (s < vl) ? acc : -1e6f;
      }
      __syncthreads();
      if (tid < 128) {
        float m = sc[tid];
#pragma unroll
        for (int off = 1; off < 64; off <<= 1) m = fmaxf(m, __shfl_xor(m, off));
        if (lane == 0) red[tid >> 6] = m;
      }
      __syncthreads();
      float gm = fmaxf(red[0], red[1]);
      if (tid < 128) {
        float p = __expf(sc[tid] - gm);
        sc[tid] = p;
        float l = p;
#pragma unroll
        for (int off = 1; off < 64; off <<= 1) l += __shfl_xor(l, off);
        if (lane == 0) red[8 + (tid >> 6)] = l;
      }
      __syncthreads();
      float inv = 1.0f / (red[8] + red[9]);
      if (tid < 128) sc[tid] *= inv;
      __syncthreads();
      // context: 1024 threads: h = tid&511, s-half = tid>>9; bf16 enc
      {
        int h = tid & 511, sh = tid >> 9;
        const unsigned short* eb =
            encbf + (size_t)b * Sd * Hd + (size_t)(sh * 64) * Hd + h;
        float acc = 0.f;
#pragma unroll 8
        for (int s = 0; s < 64; s++) acc += sc[sh * 64 + s] * bf2f(eb[(size_t)s * Hd]);
        if (sh == 1) scratch[640 + h] = acc;
        __syncthreads();
        if (tid < 512) ctxT[tid * 64 + b] = acc + scratch[640 + tid];
      }
    }
    gbar(arrive, go, ++ep, blk, tid);

    // ---- P2: GRU cell 0 ----
    cell_phase<true>(blk, tid, t, ctxT, embTf, h0prev, wLDS + W0IH, wLDS + W0HH,
                     bih0, bhh0, h0next, nullptr, scratch);
    gbar(arrive, go, ++ep, blk, tid);

    // ---- P3: GRU cell 1 ----
    cell_phase<false>(blk, tid, t, h0next, nullptr, h1prev, wLDS + W1IH,
                      wLDS + W1HH, bih1, bhh1, h1next, ys, scratch);
    gbar(arrive, go, ++ep, blk, tid);
  }
}

extern "C" void kernel_launch(void* const* d_in, const int* in_sizes, int n_in,
                              void* d_out, int out_size, void* d_ws, size_t ws_size,
                              hipStream_t stream) {
  const int* x = (const int*)d_in[0];
  const float* enc = (const float*)d_in[1];
  const float* h0 = (const float*)d_in[2];
  const int* vlen = (const int*)d_in[3];
  const float* emb = (const float*)d_in[4];
  const float* Wq = (const float*)d_in[5];
  const float* Wk = (const float*)d_in[6];
  const float* wv = (const float*)d_in[7];
  const float* W_ih0 = (const float*)d_in[8];
  const float* W_hh0 = (const float*)d_in[9];
  const float* b_ih0 = (const float*)d_in[10];
  const float* b_hh0 = (const float*)d_in[11];
  const float* W_ih1 = (const float*)d_in[12];
  const float* W_hh1 = (const float*)d_in[13];
  const float* b_ih1 = (const float*)d_in[14];
  const float* b_hh1 = (const float*)d_in[15];
  const float* Wd = (const float*)d_in[16];
  const float* bd = (const float*)d_in[17];
  float* out = (float*)d_out;

  char* p = (char*)d_ws;
  int* bar = (int*)p;
  p += 2048;
  unsigned short* kpbf = (unsigned short*)p;  // B*S*H bf16
  p += (size_t)Bd * Sd * Hd * 2;
  unsigned short* encbf = (unsigned short*)p;  // B*S*H bf16
  p += (size_t)Bd * Sd * Hd * 2;
  float* embTf = (float*)p;  // T*E*B f32
  p += (size_t)Td * Ed * Bd * 4;
  float* qpT = (float*)p;   p += (size_t)Hd * Bd * 4;
  float* ctxT = (float*)p;  p += (size_t)Hd * Bd * 4;
  float* h0TA = (float*)p;  p += (size_t)Hd * Bd * 4;
  float* h0TB = (float*)p;  p += (size_t)Hd * Bd * 4;
  float* h1TA = (float*)p;  p += (size_t)Hd * Bd * 4;
  float* h1TB = (float*)p;  p += (size_t)Hd * Bd * 4;
  float* ys = (float*)p;    // T*B*H f32

  hipMemsetAsync(bar, 0, 2048, stream);

  // kp = enc @ Wk^T -> bf16
  k_gemm_abt<false, false, true><<<dim3(128, 8), 256, 0, stream>>>(
      enc, Wk, nullptr, kpbf, Bd * Sd, Hd, Hd);
  // enc -> bf16 copy
  long nenc = (long)Bd * Sd * Hd;
  k_tobf<<<(nenc + 1023) / 1024, 1024, 0, stream>>>(enc, encbf, nenc);
  // embTf gather+transpose (f32)
  k_embT<<<Td, 256, 0, stream>>>(x, emb, embTf);
  // fused 64-step decoder
  k_decoder<<<NBLK, 1024, 0, stream>>>(encbf, h0, vlen, Wq, wv, W_ih0, W_hh0,
                                       b_ih0, b_hh0, W_ih1, W_hh1, b_ih1, b_hh1,
                                       kpbf, embTf, bar, qpT, ctxT, h0TA, h0TB,
                                       h1TA, h1TB, ys);
  // logits: ys(T*B,H) @ Wd^T + bd, out[b,t,v]
  k_gemm_abt<true, true, false><<<dim3(64, 157), 256, 0, stream>>>(
      ys, Wd, bd, out, Td * Bd, Vd, Hd);
}

// Round 9
// 6333.890 us; speedup vs baseline: 4.9873x; 1.0959x over previous
//
#include <hip/hip_runtime.h>
#include <hip/hip_bf16.h>

#define Bd 64
#define Td 64
#define Sd 128
#define Hd 512
#define Ed 256
#define Vd 10000
#define NBLK 256

// LDS weight offsets (floats)
#define W0IH 0      // 6*768
#define W0HH 4608   // 6*512
#define W1IH 7680   // 6*512
#define W1HH 10752  // 6*512
#define WTOT 13824

__device__ __forceinline__ float fast_tanh(float x) {
  float e = __expf(-2.0f * fabsf(x));
  float r = (1.0f - e) / (1.0f + e);
  return copysignf(r, x);
}
__device__ __forceinline__ float fast_sigmoid(float x) {
  return 1.0f / (1.0f + __expf(-x));
}
__device__ __forceinline__ float bf2f(unsigned short u) {
  return __uint_as_float(((unsigned int)u) << 16);
}

// software grid barrier: RELAXED spins + one release fence (writeback) before
// arrive, one acquire fence (invalidate) at exit. (r8: this was the 2.7x fix.)
__device__ __forceinline__ void gbar(int* arrive, int* go, int ep, int blk, int tid) {
  __syncthreads();
  if (tid == 0) {
    __builtin_amdgcn_fence(__ATOMIC_RELEASE, "agent");
    __hip_atomic_store(&arrive[blk], ep, __ATOMIC_RELAXED, __HIP_MEMORY_SCOPE_AGENT);
  }
  if (blk == 0) {
    if (tid < NBLK) {
      while (__hip_atomic_load(&arrive[tid], __ATOMIC_RELAXED,
                               __HIP_MEMORY_SCOPE_AGENT) < ep) {
        __builtin_amdgcn_s_sleep(1);
      }
    }
    __syncthreads();
    if (tid == 0)
      __hip_atomic_store(go, ep, __ATOMIC_RELAXED, __HIP_MEMORY_SCOPE_AGENT);
  }
  if (tid == 0) {
    while (__hip_atomic_load(go, __ATOMIC_RELAXED, __HIP_MEMORY_SCOPE_AGENT) < ep) {
      __builtin_amdgcn_s_sleep(1);
    }
    __builtin_amdgcn_fence(__ATOMIC_ACQUIRE, "agent");
  }
  __syncthreads();
}

// C[M,N] = A[M,K] @ W[N,K]^T (+bias). SWAP: out row m=(t*64+b) -> (b*T+t).
template <bool SWAP, bool BIAS, bool OB>
__global__ void k_gemm_abt(const float* __restrict__ A, const float* __restrict__ W,
                           const float* __restrict__ bias, void* __restrict__ Cv,
                           int M, int N, int K) {
  __shared__ __align__(16) float As[16][64];
  __shared__ __align__(16) float Ws[16][64];
  int m0 = blockIdx.x * 64, n0 = blockIdx.y * 64;
  int tid = threadIdx.x;
  int tx = tid & 15, ty = tid >> 4;
  float acc[4][4] = {};
  for (int k0 = 0; k0 < K; k0 += 16) {
#pragma unroll
    for (int i = 0; i < 4; i++) {
      int e = tid + i * 256;
      int r = e >> 4, c = e & 15;
      As[c][r] = A[(long)(m0 + r) * K + k0 + c];
    }
#pragma unroll
    for (int i = 0; i < 4; i++) {
      int e = tid + i * 256;
      int r = e >> 4, c = e & 15;
      int n = n0 + r;
      Ws[c][r] = (n < N) ? W[(long)n * K + k0 + c] : 0.0f;
    }
    __syncthreads();
#pragma unroll
    for (int k = 0; k < 16; k++) {
      float a_[4], w_[4];
#pragma unroll
      for (int i = 0; i < 4; i++) a_[i] = As[k][ty * 4 + i];
#pragma unroll
      for (int j = 0; j < 4; j++) w_[j] = Ws[k][tx * 4 + j];
#pragma unroll
      for (int i = 0; i < 4; i++)
#pragma unroll
        for (int j = 0; j < 4; j++) acc[i][j] += a_[i] * w_[j];
    }
    __syncthreads();
  }
#pragma unroll
  for (int i = 0; i < 4; i++) {
    int m = m0 + ty * 4 + i;
#pragma unroll
    for (int j = 0; j < 4; j++) {
      int n = n0 + tx * 4 + j;
      if (n < N) {
        float v = acc[i][j];
        if (BIAS) v += bias[n];
        long idx;
        if (SWAP) {
          int t_ = m >> 6, b_ = m & 63;
          idx = ((long)(b_ * Td + t_)) * N + n;
        } else {
          idx = (long)m * N + n;
        }
        if (OB) {
          __hip_bfloat16 h = __float2bfloat16(v);
          ((unsigned short*)Cv)[idx] = *(unsigned short*)&h;
        } else {
          ((float*)Cv)[idx] = v;
        }
      }
    }
  }
}

// elementwise f32 -> bf16 copy
__global__ void k_tobf(const float* __restrict__ src, unsigned short* __restrict__ dst,
                       long n) {
  long i = (long)blockIdx.x * 1024 + threadIdx.x;
  if (i < n) {
    __hip_bfloat16 h = __float2bfloat16(src[i]);
    dst[i] = *(unsigned short*)&h;
  }
}

// embTf[t][e][b] = emb[x[b][t]][e]  (f32)
__global__ void k_embT(const int* __restrict__ x, const float* __restrict__ emb,
                       float* __restrict__ embTf) {
  __shared__ int rows[64];
  int t = blockIdx.x;
  if (threadIdx.x < 64) rows[threadIdx.x] = x[threadIdx.x * Td + t];
  __syncthreads();
  int e = threadIdx.x;
  for (int b = 0; b < 64; b++) {
    embTf[((long)t * Ed + e) * 64 + b] = emb[(long)rows[b] * Ed + e];
  }
}

// GRU cell phase, 16 waves. Waves 0-5: ih row-dots over aT (for C0: raw ctx,
// scaled by 1/den at the end); waves 6-11: hh row-dots over hT; waves 12-14
// (C0 only): emb part. Combine + nonlinearity by threads 0-127.
template <bool C0>
__device__ __forceinline__ void cell_phase(
    int blk, int tid, int t, const float* __restrict__ aT,
    const float* __restrict__ embTf, const float* __restrict__ hT,
    const float* wIH, const float* wHH, const float* __restrict__ bih,
    const float* __restrict__ bhh, const float* __restrict__ dscale,
    float* __restrict__ houtT, float* __restrict__ ys, float* scratch) {
  int lane = tid & 63;
  int w = tid >> 6;
  const int RIH = C0 ? 768 : 512;
  float* ps = scratch;         // [12][64]
  float* psE = scratch + 768;  // [6][64]
  if (w < 6) {
    const float* wr = wIH + w * RIH;
    float acc = 0.f;
#pragma unroll 8
    for (int k = 0; k < 512; k++) acc += aT[k * 64 + lane] * wr[k];
    if (C0) acc = acc / dscale[lane];  // normalize softmax denominator
    ps[w * 64 + lane] = acc;
  } else if (w < 12) {
    const float* vr = wHH + (w - 6) * 512;
    float acc = 0.f;
#pragma unroll 8
    for (int k = 0; k < 512; k++) acc += hT[k * 64 + lane] * vr[k];
    ps[w * 64 + lane] = acc;
  } else if (C0 && w < 15) {
    int r0 = (w - 12) * 2;
    const float* w0 = wIH + r0 * 768 + 512;
    const float* w1 = wIH + (r0 + 1) * 768 + 512;
    const float* ef = embTf + (size_t)t * Ed * 64;
    float a0 = 0.f, a1 = 0.f;
#pragma unroll 8
    for (int e = 0; e < 256; e++) {
      float a = ef[e * 64 + lane];
      a0 += a * w0[e];
      a1 += a * w1[e];
    }
    psE[r0 * 64 + lane] = a0;
    psE[(r0 + 1) * 64 + lane] = a1;
  }
  __syncthreads();
  if (tid < 128) {
    int jl = tid >> 6, b = tid & 63;
    float ir = ps[(0 + jl) * 64 + b];
    float iz = ps[(2 + jl) * 64 + b];
    float in = ps[(4 + jl) * 64 + b];
    if (C0) {
      ir += psE[(0 + jl) * 64 + b];
      iz += psE[(2 + jl) * 64 + b];
      in += psE[(4 + jl) * 64 + b];
    }
    float hr = ps[(6 + jl) * 64 + b];
    float hz = ps[(8 + jl) * 64 + b];
    float hn_ = ps[(10 + jl) * 64 + b];
    int j = blk * 2 + jl;
    float r = fast_sigmoid(ir + hr + bih[j] + bhh[j]);
    float z = fast_sigmoid(iz + hz + bih[Hd + j] + bhh[Hd + j]);
    float n = fast_tanh(in + bih[2 * Hd + j] + r * (hn_ + bhh[2 * Hd + j]));
    float hp = hT[j * 64 + b];
    float out = (1.f - z) * n + z * hp;
    houtT[j * 64 + b] = out;
    if (!C0) ys[((size_t)t * 64 + b) * Hd + j] = out;
  }
}

__global__ __launch_bounds__(1024, 1) void k_decoder(
    const unsigned short* __restrict__ encbf, const float* __restrict__ h0_in,
    const int* __restrict__ vlen, const float* __restrict__ Wq,
    const float* __restrict__ wvp, const float* __restrict__ Wih0,
    const float* __restrict__ Whh0, const float* __restrict__ bih0,
    const float* __restrict__ bhh0, const float* __restrict__ Wih1,
    const float* __restrict__ Whh1, const float* __restrict__ bih1,
    const float* __restrict__ bhh1, const unsigned short* __restrict__ kpbf,
    const float* __restrict__ embTf, int* bar, float* qpT, float* ctxT,
    float* den, float* h0TA, float* h0TB, float* h1TA, float* h1TB, float* ys) {
  __shared__ __align__(16) float wLDS[WTOT];            // 55296 B
  __shared__ __align__(16) float WqL[1024];             // 4096 B
  __shared__ __align__(16) unsigned short kpL[32 * 512];   // 32768 B
  __shared__ __align__(16) unsigned short encL[32 * 512];  // 32768 B
  __shared__ __align__(16) float scratch[1280];         // 5120 B
  int blk = blockIdx.x, tid = threadIdx.x;
  int lane = tid & 63;
  int w = tid >> 6;
  int battn = blk >> 2, q = blk & 3;
  int* arrive = bar;
  int* go = bar + NBLK;
  int ep = 0;

  // ---- one-time staging ----
  {
    int j0 = blk * 2;
#pragma unroll
    for (int rr = 0; rr < 6; rr++) {
      int g = rr >> 1, jl = rr & 1;
      int row = g * Hd + j0 + jl;
      const float* s0 = Wih0 + (size_t)row * 768;
      for (int k = tid; k < 768; k += 1024) wLDS[W0IH + rr * 768 + k] = s0[k];
      const float* s1 = Whh0 + (size_t)row * Hd;
      for (int k = tid; k < Hd; k += 1024) wLDS[W0HH + rr * 512 + k] = s1[k];
      const float* s2 = Wih1 + (size_t)row * Hd;
      for (int k = tid; k < Hd; k += 1024) wLDS[W1IH + rr * 512 + k] = s2[k];
      const float* s3 = Whh1 + (size_t)row * Hd;
      for (int k = tid; k < Hd; k += 1024) wLDS[W1HH + rr * 512 + k] = s3[k];
    }
    // Wq rows 2blk, 2blk+1
    WqL[tid] = Wq[(size_t)(blk * 2 + (tid >> 9)) * Hd + (tid & 511)];
    // kp/enc slices: 32 s-rows each (contiguous 32KB), as uint4
    const uint4* ksrc = (const uint4*)(kpbf + ((size_t)battn * Sd + q * 32) * Hd);
    const uint4* esrc = (const uint4*)(encbf + ((size_t)battn * Sd + q * 32) * Hd);
    uint4* kdst = (uint4*)kpL;
    uint4* edst = (uint4*)encL;
    for (int i = tid; i < 2048; i += 1024) {
      kdst[i] = ksrc[i];
      edst[i] = esrc[i];
    }
  }
  // wv -> registers
  float wvr[8];
#pragma unroll
  for (int i = 0; i < 8; i++) wvr[i] = wvp[lane * 8 + i];

  // init: h0 transpose (blocks 0..63); zero ctxT/den
  if (blk < Bd) {
    int b = blk;
    for (int k = tid; k < Hd; k += 1024) {
      h0TA[k * 64 + b] = h0_in[(0 * Bd + b) * Hd + k];
      h1TA[k * 64 + b] = h0_in[(1 * Bd + b) * Hd + k];
    }
  }
  if (tid < 128) ctxT[blk * 128 + tid] = 0.f;
  if (blk < Bd && tid == 128) den[blk] = 0.f;
  gbar(arrive, go, ++ep, blk, tid);

  for (int t = 0; t < Td; t++) {
    const float* h0prev = (t & 1) ? h0TB : h0TA;
    float* h0next = (t & 1) ? h0TA : h0TB;
    const float* h1prev = (t & 1) ? h1TB : h1TA;
    float* h1next = (t & 1) ? h1TA : h1TB;

    // ---- P0: qproj (rows 2blk, 2blk+1 from LDS Wq; K split 8x64) ----
    {
      int rl = w >> 3, ks = w & 7;
      const float* qrow = &WqL[rl * 512 + ks * 64];
      const float* hp = h1prev + ks * 64 * 64;
      float acc = 0.f;
#pragma unroll 8
      for (int kk = 0; kk < 64; kk++) acc += hp[kk * 64 + lane] * qrow[kk];
      scratch[w * 64 + lane] = acc;
      __syncthreads();
      if (tid < 128) {
        int rl2 = tid >> 6, b = tid & 63;
        float s = 0.f;
#pragma unroll
        for (int qq = 0; qq < 8; qq++) s += scratch[(rl2 * 8 + qq) * 64 + b];
        qpT[(blk * 2 + rl2) * 64 + b] = s;
      }
    }
    gbar(arrive, go, ++ep, blk, tid);

    // ---- P1: attention partial (ALL blocks; b=battn, 32 s-rows from LDS) ----
    {
      int b = battn;
      float* sc = scratch;  // [32]
      float qv[8];
#pragma unroll
      for (int i = 0; i < 8; i++) qv[i] = qpT[(lane * 8 + i) * 64 + b];
      int vl = vlen[b];
      // scores: wave w -> s_local = 2w, 2w+1; exp without max (|score|<=~9)
#pragma unroll
      for (int si = 0; si < 2; si++) {
        int sl = w * 2 + si;
        uint4 kw = *(const uint4*)&kpL[sl * 512 + lane * 8];
        float f0 = __uint_as_float(kw.x << 16);
        float f1 = __uint_as_float(kw.x & 0xffff0000u);
        float f2 = __uint_as_float(kw.y << 16);
        float f3 = __uint_as_float(kw.y & 0xffff0000u);
        float f4 = __uint_as_float(kw.z << 16);
        float f5 = __uint_as_float(kw.z & 0xffff0000u);
        float f6 = __uint_as_float(kw.w << 16);
        float f7 = __uint_as_float(kw.w & 0xffff0000u);
        float acc = wvr[0] * fast_tanh(qv[0] + f0) + wvr[1] * fast_tanh(qv[1] + f1) +
                    wvr[2] * fast_tanh(qv[2] + f2) + wvr[3] * fast_tanh(qv[3] + f3) +
                    wvr[4] * fast_tanh(qv[4] + f4) + wvr[5] * fast_tanh(qv[5] + f5) +
                    wvr[6] * fast_tanh(qv[6] + f6) + wvr[7] * fast_tanh(qv[7] + f7);
#pragma unroll
        for (int off = 1; off < 64; off <<= 1) acc += __shfl_xor(acc, off);
        if (lane == 0) {
          int s = q * 32 + sl;
          sc[sl] = (s < vl) ? __expf(acc) : 0.f;
        }
      }
      __syncthreads();
      // partial denominator
      if (tid < 32) {
        float p = sc[tid];
#pragma unroll
        for (int off = 1; off < 32; off <<= 1) p += __shfl_xor(p, off, 32);
        if (tid == 0) atomicAdd(&den[b], p);
      }
      // partial context (unnormalized), accumulate via fp32 atomics
      if (tid < 512) {
        float acc = 0.f;
#pragma unroll 8
        for (int s = 0; s < 32; s++) acc += sc[s] * bf2f(encL[s * 512 + tid]);
        atomicAdd(&ctxT[tid * 64 + b], acc);
      }
    }
    gbar(arrive, go, ++ep, blk, tid);

    // ---- P2: GRU cell 0 (ctx scaled by 1/den inside) ----
    cell_phase<true>(blk, tid, t, ctxT, embTf, h0prev, wLDS + W0IH, wLDS + W0HH,
                     bih0, bhh0, den, h0next, nullptr, scratch);
    gbar(arrive, go, ++ep, blk, tid);

    // ---- P3: GRU cell 1 + zero ctxT/den for next step ----
    if (tid < 128) ctxT[blk * 128 + tid] = 0.f;
    if (blk < Bd && tid == 128) den[blk] = 0.f;
    cell_phase<false>(blk, tid, t, h0next, nullptr, h1prev, wLDS + W1IH,
                      wLDS + W1HH, bih1, bhh1, nullptr, h1next, ys, scratch);
    gbar(arrive, go, ++ep, blk, tid);
  }
}

extern "C" void kernel_launch(void* const* d_in, const int* in_sizes, int n_in,
                              void* d_out, int out_size, void* d_ws, size_t ws_size,
                              hipStream_t stream) {
  const int* x = (const int*)d_in[0];
  const float* enc = (const float*)d_in[1];
  const float* h0 = (const float*)d_in[2];
  const int* vlen = (const int*)d_in[3];
  const float* emb = (const float*)d_in[4];
  const float* Wq = (const float*)d_in[5];
  const float* Wk = (const float*)d_in[6];
  const float* wv = (const float*)d_in[7];
  const float* W_ih0 = (const float*)d_in[8];
  const float* W_hh0 = (const float*)d_in[9];
  const float* b_ih0 = (const float*)d_in[10];
  const float* b_hh0 = (const float*)d_in[11];
  const float* W_ih1 = (const float*)d_in[12];
  const float* W_hh1 = (const float*)d_in[13];
  const float* b_ih1 = (const float*)d_in[14];
  const float* b_hh1 = (const float*)d_in[15];
  const float* Wd = (const float*)d_in[16];
  const float* bd = (const float*)d_in[17];
  float* out = (float*)d_out;

  char* p = (char*)d_ws;
  int* bar = (int*)p;
  p += 2048;
  unsigned short* kpbf = (unsigned short*)p;  // B*S*H bf16
  p += (size_t)Bd * Sd * Hd * 2;
  unsigned short* encbf = (unsigned short*)p;  // B*S*H bf16
  p += (size_t)Bd * Sd * Hd * 2;
  float* embTf = (float*)p;  // T*E*B f32
  p += (size_t)Td * Ed * Bd * 4;
  float* qpT = (float*)p;   p += (size_t)Hd * Bd * 4;
  float* ctxT = (float*)p;  p += (size_t)Hd * Bd * 4;
  float* den = (float*)p;   p += 256;
  float* h0TA = (float*)p;  p += (size_t)Hd * Bd * 4;
  float* h0TB = (float*)p;  p += (size_t)Hd * Bd * 4;
  float* h1TA = (float*)p;  p += (size_t)Hd * Bd * 4;
  float* h1TB = (float*)p;  p += (size_t)Hd * Bd * 4;
  float* ys = (float*)p;    // T*B*H f32

  hipMemsetAsync(bar, 0, 2048, stream);

  // kp = enc @ Wk^T -> bf16
  k_gemm_abt<false, false, true><<<dim3(128, 8), 256, 0, stream>>>(
      enc, Wk, nullptr, kpbf, Bd * Sd, Hd, Hd);
  // enc -> bf16 copy
  long nenc = (long)Bd * Sd * Hd;
  k_tobf<<<(nenc + 1023) / 1024, 1024, 0, stream>>>(enc, encbf, nenc);
  // embTf gather+transpose (f32)
  k_embT<<<Td, 256, 0, stream>>>(x, emb, embTf);
  // fused 64-step decoder
  k_decoder<<<NBLK, 1024, 0, stream>>>(encbf, h0, vlen, Wq, wv, W_ih0, W_hh0,
                                       b_ih0, b_hh0, W_ih1, W_hh1, b_ih1, b_hh1,
                                       kpbf, embTf, bar, qpT, ctxT, den, h0TA,
                                       h0TB, h1TA, h1TB, ys);
  // logits: ys(T*B,H) @ Wd^T + bd, out[b,t,v]
  k_gemm_abt<true, true, false><<<dim3(64, 157), 256, 0, stream>>>(
      ys, Wd, bd, out, Td * Bd, Vd, Hd);
}